// Round 16
// baseline (428.255 us; speedup 1.0000x reference)
//
#include <hip/hip_runtime.h>
#include <math.h>

#define NN 1024
#define BB 32
#define TT 12
#define HH 64
#define K1 65
#define NCOLS (BB * K1)   // 2080 valid columns
#define BPAD 72           // per-b column stride (16B-aligned fp16 rows)
#define NC2 (BB * BPAD)   // 2304 = 18*128
#define NH (NN * HH)      // 65536
#define KX 1024           // K: fp16 (A and X)
#define BM 128
#define BN 256
#define BKK 32
#define NBUF 3
#define PTS 264           // epilogue LDS tile stride (f16)

typedef __attribute__((ext_vector_type(8))) _Float16 h8;
typedef __attribute__((ext_vector_type(4))) float f32x4;
typedef __attribute__((ext_vector_type(16))) float f32x16;

__device__ __forceinline__ void gload16(const void* g, void* l) {
    __builtin_amdgcn_global_load_lds((__attribute__((address_space(1))) void*)g,
                                     (__attribute__((address_space(3))) void*)l,
                                     16, 0, 0);
}

// ---------------- row-sum -> d^{-1/2} (both matrices in one launch) ----------
__global__ void rowsum_rsqrt2(const float* __restrict__ M0, const float* __restrict__ M1,
                              float* __restrict__ ds0, float* __restrict__ ds1) {
    int bid = blockIdx.x;
    const float* p = (bid < NN ? M0 : M1) + (size_t)(bid & (NN - 1)) * NN;
    float* ds = (bid < NN ? ds0 : ds1) + (bid & (NN - 1));
    float s = 0.f;
    for (int i = threadIdx.x; i < NN; i += blockDim.x) s += p[i];
    __shared__ float red[256];
    red[threadIdx.x] = s;
    __syncthreads();
    for (int off = 128; off; off >>= 1) {
        if (threadIdx.x < off) red[threadIdx.x] += red[threadIdx.x + off];
        __syncthreads();
    }
    if (threadIdx.x == 0) {
        float d = red[0];
        *ds = d > 0.f ? 1.0f / sqrtf(d) : 0.f;
    }
}

// ---------------- build A_t fp16: A2[t][m][n] ----------------
__global__ void build_A2(const float* __restrict__ dtw, const float* __restrict__ adj,
                         const float* __restrict__ spec, const float* __restrict__ td,
                         const float* __restrict__ dsA, const float* __restrict__ dsS,
                         const int* __restrict__ sr_ptr, _Float16* __restrict__ A2) {
    int idx = blockIdx.x * blockDim.x + threadIdx.x;
    int m = idx >> 10, n = idx & 1023;
    float sr = (float)sr_ptr[0];
    float dtw_v = dtw[idx], adj_v = adj[idx], spec_v = spec[idx], td_v = td[idx];
    float I = (m == n) ? 1.f : 0.f;
    float Lspec = I - dsS[m] * spec_v * dsS[n];
    float Ladj  = I - dsA[m] * adj_v * dsA[n];
    float tind = (float)TT - ceilf(fabsf(td_v) / sr);
    float base2 = 0.5f * (Lspec + I);
    float base3 = (Lspec + Ladj + I) * (1.f / 3.f);
    bool nz = (dtw_v != 0.f);
#pragma unroll
    for (int t = 0; t < TT; ++t) {
        bool act = nz && ((float)(t + 1) > tind);
        float a = (t == TT - 1) ? base3 + (act ? dtw_v * (1.f / 3.f) : 0.f)
                                : base2 + (act ? dtw_v * 0.5f : 0.f);
        A2[((size_t)t * NN + m) * KX + n] = (_Float16)a;
    }
}

// ---------------- build cat (transposed, fp16): cat[z][col][node], col=b*72+k1 ----
__global__ __launch_bounds__(256) void build_cat(
    const float* __restrict__ inputs, const float* __restrict__ states,
    const _Float16* __restrict__ rall, _Float16* __restrict__ cat,
    int tbase, int pass2) {
    __shared__ float hs[64][68];
    __shared__ float rs[64][68];
    const int z = blockIdx.z, t = tbase + z;
    const int b = blockIdx.y, nb = blockIdx.x;
    const int tid = threadIdx.x;
    const float* sb = states + ((size_t)t * BB + b) * NH + (size_t)nb * 4096;
    const float4* src = (const float4*)sb;
#pragma unroll
    for (int q = 0; q < 4; ++q) {
        float4 v = src[tid * 4 + q];
        int fi = tid * 16 + q * 4;
        *(float4*)&hs[fi >> 6][fi & 63] = v;
    }
    if (pass2) {
        const _Float16* rb = rall + ((size_t)t * BB + b) * NH + (size_t)nb * 4096;
#pragma unroll
        for (int i = 0; i < 16; ++i) {
            int fi = tid * 16 + i;
            rs[fi >> 6][fi & 63] = (float)rb[fi];
        }
    }
    __syncthreads();
    _Float16* catz = cat + (size_t)z * NC2 * KX;
    int jp = tid >> 2, ni = (tid & 3) << 4;
    int col = b * BPAD + 1 + jp;   // feature k1 = 1 + jp
    __attribute__((aligned(16))) _Float16 hib[16];
#pragma unroll
    for (int i = 0; i < 16; ++i) {
        float v = hs[ni + i][jp];
        if (pass2) v *= rs[ni + i][jp];
        hib[i] = (_Float16)v;
    }
    size_t dst = (size_t)col * KX + nb * 64 + ni;
    *(uint4*)(catz + dst)     = *(uint4*)&hib[0];
    *(uint4*)(catz + dst + 8) = *(uint4*)&hib[8];
    if (tid < 64) {
        float v = inputs[((size_t)b * TT + t) * NN + nb * 64 + tid];
        catz[(size_t)(b * BPAD) * KX + nb * 64 + tid] = (_Float16)v;   // k1 = 0 (x)
    }
}

// ---------------- pass-2 cat update in place (C=12 path): cat *= r ----------
__global__ __launch_bounds__(256) void scale_cat(
    const _Float16* __restrict__ rall, _Float16* __restrict__ cat, int tbase) {
    __shared__ float rs[64][68];    // rs[node][hh]
    const int z = blockIdx.z, t = tbase + z;
    const int b = blockIdx.y, nb = blockIdx.x;
    const int tid = threadIdx.x;
    const _Float16* rb = rall + ((size_t)t * BB + b) * NH + (size_t)nb * 4096;
    {
        h8 r0 = *(const h8*)(rb + tid * 16);
        h8 r1 = *(const h8*)(rb + tid * 16 + 8);
        int node = tid >> 2, c0 = (tid & 3) << 4;
#pragma unroll
        for (int i = 0; i < 8; ++i) {
            rs[node][c0 + i]     = (float)r0[i];
            rs[node][c0 + 8 + i] = (float)r1[i];
        }
    }
    __syncthreads();
    _Float16* catz = cat + (size_t)z * NC2 * KX;
    const int jp = tid >> 2, ni = (tid & 3) << 4;
    const int col = b * BPAD + 1 + jp;
    size_t dst = (size_t)col * KX + nb * 64 + ni;
    h8 v0 = *(const h8*)(catz + dst);
    h8 v1 = *(const h8*)(catz + dst + 8);
    h8 o0, o1;
#pragma unroll
    for (int i = 0; i < 8; ++i) {
        o0[i] = (_Float16)((float)v0[i] * rs[ni + i][jp]);
        o1[i] = (_Float16)((float)v1[i] * rs[ni + 8 + i][jp]);
    }
    *(h8*)(catz + dst)     = o0;
    *(h8*)(catz + dst + 8) = o1;
}

// ---- MFMA GEMM (fp16, K=1024): 128x256 block, 8 waves (64x64 each), 3-buf ----
// ---- counted vmcnt, 32x32x16 MFMA; 16 waves/CU for latency hiding ----
__global__ __launch_bounds__(512, 2) void gemm_f16(
    const _Float16* __restrict__ A2, const _Float16* __restrict__ cat,
    _Float16* __restrict__ P, int tbase) {
    __shared__ __align__(16) _Float16 smem[NBUF * (BM + BN) * BKK];   // 72 KB
    _Float16* Asb = smem;                       // [NBUF][BM*BKK]
    _Float16* Xsb = smem + NBUF * BM * BKK;     // [NBUF][BN*BKK]
    const int tid = threadIdx.x;
    const int lane = tid & 63;
    const int wid = tid >> 6;           // 0..7
    const int wr = wid >> 2;            // 0..1  row half (64 rows each)
    const int wc = wid & 3;             // 0..3  col quarter (64 cols each)
    int bid = blockIdx.x;
    int l = (bid & 7) * ((int)gridDim.x >> 3) + (bid >> 3);
    int z = l / 72; int r = l - z * 72;
    int g  = r / 12, w = r - g * 12;
    int gy = g & 1, gx = g >> 1;          // gx in [0,3)
    int by = (gy << 2) + (w & 3);         // 0..7
    int bx = gx * 3 + (w >> 2);           // 0..8
    const int m0 = by * BM;
    const int n0 = bx * BN;
    const _Float16* Ab = A2 + (size_t)(tbase + z) * NN * KX + (size_t)m0 * KX;
    const _Float16* Xb = cat + (size_t)z * NC2 * KX + (size_t)n0 * KX;

    // 2 row-tiles x 2 col-tiles of 32x32 accumulators per wave (64x64)
    f32x16 acc[2][2];
#pragma unroll
    for (int i = 0; i < 2; ++i)
#pragma unroll
        for (int j = 0; j < 2; ++j)
#pragma unroll
            for (int q = 0; q < 16; ++q) acc[i][j][q] = 0.f;

    const int rl = lane & 31;      // row/col within 32-tile
    const int ko = lane >> 5;      // k-octet selector (0/1)

    // stage: 3 gload16/thread (A:1, X:2); chunk p -> dest p*16B (linear)
    auto stage = [&](int buf, int k0) {
        {
            int p = tid;                    // 0..511
            int row = p & 127;
            int kg  = p >> 7;               // 0..3
            gload16(Ab + (size_t)row * KX + k0 + kg * 8, &Asb[(size_t)(buf * BM * BKK + p * 8)]);
        }
#pragma unroll
        for (int c = 0; c < 2; ++c) {
            int p = c * 512 + tid;          // 0..1023
            int row = p & 255;
            int kg  = p >> 8;               // 0..3
            gload16(Xb + (size_t)row * KX + k0 + kg * 8, &Xsb[(size_t)(buf * BN * BKK + p * 8)]);
        }
    };
    auto compute = [&](int buf) {
#pragma unroll
        for (int ks = 0; ks < 2; ++ks) {           // k-halves of the 32-k slab
            const int oct = (ks << 1) + ko;        // octet 0..3 within slab
            h8 a[2], x[2];
#pragma unroll
            for (int i = 0; i < 2; ++i)
                a[i] = *(const h8*)&Asb[(size_t)(buf * BM * BKK + ((oct << 7) + (wr << 6) + (i << 5) + rl) * 8)];
#pragma unroll
            for (int j = 0; j < 2; ++j)
                x[j] = *(const h8*)&Xsb[(size_t)(buf * BN * BKK + ((oct << 8) + (wc << 6) + (j << 5) + rl) * 8)];
#pragma unroll
            for (int i = 0; i < 2; ++i)
#pragma unroll
                for (int j = 0; j < 2; ++j)
                    acc[i][j] = __builtin_amdgcn_mfma_f32_32x32x16_f16(a[i], x[j], acc[i][j], 0, 0, 0);
        }
    };

    stage(0, 0);
    stage(1, BKK);
    const int nk = KX / BKK;   // 32
    for (int it = 0; it < nk; ++it) {
        const int cur = it % 3;
        if (it + 2 < nk) {
            stage((it + 2) % 3, (it + 2) * BKK);
            // 3 stages in flight (9 loads/thread); wait oldest 3 -> cur ready
            asm volatile("s_waitcnt vmcnt(6)" ::: "memory");
        } else if (it + 1 < nk) {
            asm volatile("s_waitcnt vmcnt(3)" ::: "memory");
        } else {
            asm volatile("s_waitcnt vmcnt(0)" ::: "memory");
        }
        __builtin_amdgcn_s_barrier();      // cur fully written (all waves)
        compute(cur);
        __builtin_amdgcn_s_barrier();      // all waves done reading cur before re-stage
    }

    // ---- epilogue: repack through LDS, store coalesced uint4 (8 fp16/store) ----
    // acc[i][j][reg]: row = wr*64 + i*32 + (reg&3) + 8*(reg>>2) + 4*ko,
    //                 col = wc*64 + j*32 + rl
    _Float16* Pt = smem;                   // 128 x PTS fp16, aliases staging
#pragma unroll
    for (int i = 0; i < 2; ++i)
#pragma unroll
        for (int j = 0; j < 2; ++j)
#pragma unroll
            for (int q = 0; q < 16; ++q) {
                int row = (wr << 6) + (i << 5) + (q & 3) + ((q >> 2) << 3) + (ko << 2);
                Pt[row * PTS + (wc << 6) + (j << 5) + rl] = (_Float16)acc[i][j][q];
            }
    __syncthreads();
    _Float16* Pz = P + (size_t)z * NN * NC2;
    const int rr = tid >> 5;   // 0..15
    const int cc = tid & 31;   // 0..31
#pragma unroll
    for (int c = 0; c < 8; ++c) {
        int row = rr + (c << 4);
        uint4 v = *(const uint4*)&Pt[row * PTS + cc * 8];
        *(uint4*)(Pz + (size_t)(m0 + row) * NC2 + n0 + cc * 8) = v;
    }
}

// ---------------- fused pass-1 stage2 (MFMA): prefix over zc t's in AGPRs ----
__global__ __launch_bounds__(256) void stage2m(const _Float16* __restrict__ P,
                                               const float* __restrict__ W,
                                               const float* __restrict__ bias,
                                               float* __restrict__ cum,
                                               _Float16* __restrict__ rall,
                                               int tbase, int zc) {
    __shared__ __align__(16) _Float16 Pl[TT * NC2];   // 55.3 KB
    __shared__ _Float16 Wl[K1 * 128];                 // 16.6 KB
    const int m = blockIdx.x;
    const int tid = threadIdx.x;
    const int lane = tid & 63, wid = tid >> 6;
    const int fl = lane & 15, fh = lane >> 4;
    for (int i = tid; i < K1 * 128; i += 256) Wl[i] = (_Float16)W[i];
    const int chunks = zc * (NC2 / 8);
    for (int idx = tid; idx < chunks; idx += 256) {
        int z = idx / (NC2 / 8), off = idx - z * (NC2 / 8);
        gload16(P + ((size_t)z * NN + m) * NC2 + off * 8, (char*)Pl + (size_t)idx * 16);
    }
    __syncthreads();
    const int nt0 = wid * 2;
    h8 wf[2][2];
    float w64[2], bvv[2];
#pragma unroll
    for (int n2 = 0; n2 < 2; ++n2) {
        int k2 = (nt0 + n2) * 16 + fl;
        w64[n2] = (float)Wl[64 * 128 + k2];
        bvv[n2] = bias[k2];
#pragma unroll
        for (int ks = 0; ks < 2; ++ks) {
            h8 tmp;
#pragma unroll
            for (int j = 0; j < 8; ++j)
                tmp[j] = Wl[(ks * 32 + fh * 8 + j) * 128 + k2];
            wf[n2][ks] = tmp;
        }
    }
    f32x4 g[2][2];
    if (tbase > 0) {
#pragma unroll
        for (int mt = 0; mt < 2; ++mt)
#pragma unroll
            for (int n2 = 0; n2 < 2; ++n2)
#pragma unroll
                for (int r4 = 0; r4 < 4; ++r4) {
                    int b = mt * 16 + fh * 4 + r4;
                    int k2 = (nt0 + n2) * 16 + fl;
                    g[mt][n2][r4] = cum[(size_t)b * (2 * NH) + (size_t)m * 128 + k2];
                }
    } else {
#pragma unroll
        for (int mt = 0; mt < 2; ++mt)
#pragma unroll
            for (int n2 = 0; n2 < 2; ++n2)
                g[mt][n2] = {0.f, 0.f, 0.f, 0.f};
    }
#pragma unroll 1
    for (int z = 0; z < zc; ++z) {
        const _Float16* Pz = &Pl[z * NC2];
        h8 af[2][2];
#pragma unroll
        for (int mt = 0; mt < 2; ++mt)
#pragma unroll
            for (int ks = 0; ks < 2; ++ks)
                af[mt][ks] = *(const h8*)&Pz[(mt * 16 + fl) * BPAD + ks * 32 + fh * 8];
#pragma unroll
        for (int mt = 0; mt < 2; ++mt)
#pragma unroll
            for (int n2 = 0; n2 < 2; ++n2)
#pragma unroll
                for (int ks = 0; ks < 2; ++ks)
                    g[mt][n2] = __builtin_amdgcn_mfma_f32_16x16x32_f16(
                        af[mt][ks], wf[n2][ks], g[mt][n2], 0, 0, 0);
        float p64[2][4];
#pragma unroll
        for (int mt = 0; mt < 2; ++mt)
#pragma unroll
            for (int r4 = 0; r4 < 4; ++r4)
                p64[mt][r4] = (float)Pz[(mt * 16 + fh * 4 + r4) * BPAD + 64];
#pragma unroll
        for (int mt = 0; mt < 2; ++mt)
#pragma unroll
            for (int n2 = 0; n2 < 2; ++n2)
#pragma unroll
                for (int r4 = 0; r4 < 4; ++r4)
                    g[mt][n2][r4] += p64[mt][r4] * w64[n2] + bvv[n2];
        if (m < 512) {   // r-half: f = m*128 + k2 < NH
            const int t = tbase + z;
#pragma unroll
            for (int mt = 0; mt < 2; ++mt)
#pragma unroll
                for (int n2 = 0; n2 < 2; ++n2)
#pragma unroll
                    for (int r4 = 0; r4 < 4; ++r4) {
                        int b = mt * 16 + fh * 4 + r4;
                        int k2 = (nt0 + n2) * 16 + fl;
                        float rv = 1.f / (1.f + expf(-g[mt][n2][r4]));
                        rall[((size_t)t * BB + b) * NH + (size_t)m * 128 + k2] = (_Float16)rv;
                    }
        }
    }
    if (m >= 512 || tbase + zc < TT) {
#pragma unroll
        for (int mt = 0; mt < 2; ++mt)
#pragma unroll
            for (int n2 = 0; n2 < 2; ++n2)
#pragma unroll
                for (int r4 = 0; r4 < 4; ++r4) {
                    int b = mt * 16 + fh * 4 + r4;
                    int k2 = (nt0 + n2) * 16 + fl;
                    cum[(size_t)b * (2 * NH) + (size_t)m * 128 + k2] = g[mt][n2][r4];
                }
    }
}

// ------- pass-2 stage2 fused w/ finalize (C=12): gcn2 = sumP@W2 + 12*b2 -> out -------
__global__ __launch_bounds__(128) void stage2p2f(const _Float16* __restrict__ P,
                                                 const float* __restrict__ W,
                                                 const float* __restrict__ bias,
                                                 const float* __restrict__ cum1,
                                                 const float* __restrict__ states,
                                                 float* __restrict__ out, int zc) {
    __shared__ float Pl[K1][37];
    __shared__ float Wl[K1 * 64];
    const int m = blockIdx.x;
    for (int i = threadIdx.x; i < K1 * 64; i += 128) Wl[i] = W[i];
    for (int i = threadIdx.x; i < NCOLS; i += 128) {
        int b = i / K1, k = i - b * K1;
        float s = 0.f;
        for (int z = 0; z < zc; ++z)
            s += (float)P[((size_t)z * NN + m) * NC2 + b * BPAD + k];
        Pl[k][b] = s;
    }
    __syncthreads();
    const int k2q = (threadIdx.x & 15) << 2;   // 0..60
    const int bq4 = (threadIdx.x >> 4) << 2;   // 0,4,..,28
    const float4 bv = *(const float4*)(bias + k2q);

    for (int bi = 0; bi < 4; ++bi) {
        const int b = bq4 + bi;
        float a0 = 0.f, a1 = 0.f, a2 = 0.f, a3 = 0.f;
#pragma unroll 4
        for (int k = 0; k < K1; ++k) {
            float p = Pl[k][b];
            float4 w4 = *(const float4*)&Wl[k * 64 + k2q];
            a0 += p * w4.x; a1 += p * w4.y; a2 += p * w4.z; a3 += p * w4.w;
        }
        const int f = m * HH + k2q;
        float g0 = a0 + zc * bv.x, g1 = a1 + zc * bv.y;
        float g2 = a2 + zc * bv.z, g3 = a3 + zc * bv.w;
        const float4 ul = *(const float4*)(cum1 + (size_t)b * 2 * NH + NH + f);
        const float4 hv = *(const float4*)(states + ((size_t)(TT - 1) * BB + b) * NH + f);
        float4 ov;
        { float u = 1.f / (1.f + expf(-ul.x)); ov.x = u * hv.x + (1.f - u) * tanhf(g0); }
        { float u = 1.f / (1.f + expf(-ul.y)); ov.y = u * hv.y + (1.f - u) * tanhf(g1); }
        { float u = 1.f / (1.f + expf(-ul.z)); ov.z = u * hv.z + (1.f - u) * tanhf(g2); }
        { float u = 1.f / (1.f + expf(-ul.w)); ov.w = u * hv.w + (1.f - u) * tanhf(g3); }
        *(float4*)(out + (size_t)b * NH + f) = ov;
        *(float4*)(out + (size_t)BB * NH + (size_t)b * NH + f) = ov;
    }
}

// ---------------- fallback pass-2 stage2 (+ separate finalize) ------
__global__ __launch_bounds__(128) void stage2p2(const _Float16* __restrict__ P,
                                                const float* __restrict__ W,
                                                const float* __restrict__ bias,
                                                float* __restrict__ cum, int zc) {
    __shared__ float Pl[K1][37];
    __shared__ float Wl[K1 * 64];
    const int m = blockIdx.x;
    for (int i = threadIdx.x; i < K1 * 64; i += 128) Wl[i] = W[i];
    for (int i = threadIdx.x; i < NCOLS; i += 128) {
        int b = i / K1, k = i - b * K1;
        float s = 0.f;
        for (int z = 0; z < zc; ++z)
            s += (float)P[((size_t)z * NN + m) * NC2 + b * BPAD + k];
        Pl[k][b] = s;
    }
    __syncthreads();
    const int k2q = (threadIdx.x & 15) << 2;
    const int bq4 = (threadIdx.x >> 4) << 2;
    const float4 bv = *(const float4*)(bias + k2q);

    for (int bi = 0; bi < 4; ++bi) {
        const int b = bq4 + bi;
        float a0 = 0.f, a1 = 0.f, a2 = 0.f, a3 = 0.f;
#pragma unroll 4
        for (int k = 0; k < K1; ++k) {
            float p = Pl[k][b];
            float4 w4 = *(const float4*)&Wl[k * 64 + k2q];
            a0 += p * w4.x; a1 += p * w4.y; a2 += p * w4.z; a3 += p * w4.w;
        }
        float* cp = cum + (size_t)b * NN * 64 + (size_t)m * 64 + k2q;
        float4 c4 = *(float4*)cp;
        c4.x += a0 + zc * bv.x; c4.y += a1 + zc * bv.y;
        c4.z += a2 + zc * bv.z; c4.w += a3 + zc * bv.w;
        *(float4*)cp = c4;
    }
}

__global__ void finalize(const float* __restrict__ cum1, const float* __restrict__ cum2,
                         const float* __restrict__ states, float* __restrict__ out) {
    int idx = blockIdx.x * blockDim.x + threadIdx.x;
    if (idx >= BB * NH) return;
    int b = idx >> 16;
    int f = idx & (NH - 1);
    float u = 1.f / (1.f + expf(-cum1[(size_t)b * 2 * NH + NH + f]));
    float h = states[((size_t)(TT - 1) * BB + b) * NH + f];
    float c = tanhf(cum2[idx]);
    float o = u * h + (1.f - u) * c;
    out[idx] = o;
    out[(size_t)BB * NH + idx] = o;
}

extern "C" void kernel_launch(void* const* d_in, const int* in_sizes, int n_in,
                              void* d_out, int out_size, void* d_ws, size_t ws_size,
                              hipStream_t stream) {
    const float* inputs = (const float*)d_in[0];
    const float* states = (const float*)d_in[1];
    const float* dtw    = (const float*)d_in[2];
    const float* adj    = (const float*)d_in[3];
    const float* spec   = (const float*)d_in[4];
    const float* td     = (const float*)d_in[5];
    const float* W1     = (const float*)d_in[6];
    const float* b1     = (const float*)d_in[7];
    const float* W2     = (const float*)d_in[8];
    const float* b2     = (const float*)d_in[9];
    const int*   sr     = (const int*)d_in[10];
    float* out = (float*)d_out;

    char* ws = (char*)d_ws;
    const size_t szA2   = (size_t)TT * NN * KX * 2;     // 25.2 MB
    const size_t szCum1 = (size_t)BB * 2 * NH * 4;      // 16.8 MB
    const size_t szCum2 = (size_t)BB * NH * 4;          // 8.4 MB
    const size_t szRall = (size_t)TT * BB * NH * 2;     // 50.3 MB

    _Float16* A2  = (_Float16*)ws;
    float* cum1 = (float*)(ws + szA2);
    float* cum2 = (float*)(ws + szA2 + szCum1);
    float* dsA  = (float*)(ws + szA2 + szCum1 + szCum2);
    float* dsS  = (float*)(ws + szA2 + szCum1 + szCum2 + 4096);
    _Float16* rall = (_Float16*)(ws + szA2 + szCum1 + szCum2 + 8192);
    size_t offRest = szA2 + szCum1 + szCum2 + 8192 + szRall;

    rowsum_rsqrt2<<<2 * NN, 256, 0, stream>>>(adj, spec, dsA, dsS);
    build_A2<<<(NN * NN) / 256, 256, 0, stream>>>(dtw, adj, spec, td, dsA, dsS, sr, A2);

    const size_t szCatZ = (size_t)NC2 * KX * 2;         // 4.72 MB per t
    const size_t szPZ   = (size_t)NN * NC2 * 2;         // 4.72 MB per t
    int C;
    if      (ws_size >= offRest + 12 * (szCatZ + szPZ)) C = 12;
    else if (ws_size >= offRest + 4 * (szCatZ + szPZ))  C = 4;
    else                                                C = 1;
    _Float16* cat = (_Float16*)(ws + offRest);
    _Float16* P16 = (_Float16*)(ws + offRest + (size_t)C * szCatZ);

    if (C == 12) {
        // pass 1
        build_cat<<<dim3(16, 32, 12), 256, 0, stream>>>(inputs, states, nullptr, cat, 0, 0);
        gemm_f16<<<dim3(72 * 12), 512, 0, stream>>>(A2, cat, P16, 0);
        stage2m<<<NN, 256, 0, stream>>>(P16, W1, b1, cum1, rall, 0, 12);
        // pass 2: scale cat in place, gemm, fused stage2+finalize
        scale_cat<<<dim3(16, 32, 12), 256, 0, stream>>>(rall, cat, 0);
        gemm_f16<<<dim3(72 * 12), 512, 0, stream>>>(A2, cat, P16, 0);
        stage2p2f<<<NN, 128, 0, stream>>>(P16, W2, b2, cum1, states, out, 12);
    } else {
        hipMemsetAsync(cum2, 0, szCum2, stream);
        for (int tb = 0; tb < TT; tb += C) {
            build_cat<<<dim3(16, 32, C), 256, 0, stream>>>(inputs, states, nullptr, cat, tb, 0);
            gemm_f16<<<dim3(72 * C), 512, 0, stream>>>(A2, cat, P16, tb);
            stage2m<<<NN, 256, 0, stream>>>(P16, W1, b1, cum1, rall, tb, C);
        }
        for (int tb = 0; tb < TT; tb += C) {
            build_cat<<<dim3(16, 32, C), 256, 0, stream>>>(inputs, states, rall, cat, tb, 1);
            gemm_f16<<<dim3(72 * C), 512, 0, stream>>>(A2, cat, P16, tb);
            stage2p2<<<NN, 128, 0, stream>>>(P16, W2, b2, cum2, C);
        }
        finalize<<<(BB * NH + 255) / 256, 256, 0, stream>>>(cum1, cum2, states, out);
    }
}

// Round 17
// 395.567 us; speedup vs baseline: 1.0826x; 1.0826x over previous
//
#include <hip/hip_runtime.h>
#include <math.h>

#define NN 1024
#define BB 32
#define TT 12
#define HH 64
#define K1 65
#define NCOLS (BB * K1)   // 2080 valid columns
#define BPAD 72           // per-b column stride (16B-aligned fp16 rows)
#define NC2 (BB * BPAD)   // 2304 = 18*128
#define NH (NN * HH)      // 65536
#define KX 1024           // K: fp16 (A and X)
#define BM 128
#define BN 256
#define BKK 32
#define NBUF 2
#define PTS 264           // epilogue LDS tile stride (f16)

typedef __attribute__((ext_vector_type(8))) _Float16 h8;
typedef __attribute__((ext_vector_type(4))) float f32x4;
typedef __attribute__((ext_vector_type(16))) float f32x16;

__device__ __forceinline__ void gload16(const void* g, void* l) {
    __builtin_amdgcn_global_load_lds((__attribute__((address_space(1))) void*)g,
                                     (__attribute__((address_space(3))) void*)l,
                                     16, 0, 0);
}

// ---------------- row-sum -> d^{-1/2} (both matrices in one launch) ----------
__global__ void rowsum_rsqrt2(const float* __restrict__ M0, const float* __restrict__ M1,
                              float* __restrict__ ds0, float* __restrict__ ds1) {
    int bid = blockIdx.x;
    const float* p = (bid < NN ? M0 : M1) + (size_t)(bid & (NN - 1)) * NN;
    float* ds = (bid < NN ? ds0 : ds1) + (bid & (NN - 1));
    float s = 0.f;
    for (int i = threadIdx.x; i < NN; i += blockDim.x) s += p[i];
    __shared__ float red[256];
    red[threadIdx.x] = s;
    __syncthreads();
    for (int off = 128; off; off >>= 1) {
        if (threadIdx.x < off) red[threadIdx.x] += red[threadIdx.x + off];
        __syncthreads();
    }
    if (threadIdx.x == 0) {
        float d = red[0];
        *ds = d > 0.f ? 1.0f / sqrtf(d) : 0.f;
    }
}

// ---------------- build A_t fp16: A2[t][m][n] ----------------
__global__ void build_A2(const float* __restrict__ dtw, const float* __restrict__ adj,
                         const float* __restrict__ spec, const float* __restrict__ td,
                         const float* __restrict__ dsA, const float* __restrict__ dsS,
                         const int* __restrict__ sr_ptr, _Float16* __restrict__ A2) {
    int idx = blockIdx.x * blockDim.x + threadIdx.x;
    int m = idx >> 10, n = idx & 1023;
    float sr = (float)sr_ptr[0];
    float dtw_v = dtw[idx], adj_v = adj[idx], spec_v = spec[idx], td_v = td[idx];
    float I = (m == n) ? 1.f : 0.f;
    float Lspec = I - dsS[m] * spec_v * dsS[n];
    float Ladj  = I - dsA[m] * adj_v * dsA[n];
    float tind = (float)TT - ceilf(fabsf(td_v) / sr);
    float base2 = 0.5f * (Lspec + I);
    float base3 = (Lspec + Ladj + I) * (1.f / 3.f);
    bool nz = (dtw_v != 0.f);
#pragma unroll
    for (int t = 0; t < TT; ++t) {
        bool act = nz && ((float)(t + 1) > tind);
        float a = (t == TT - 1) ? base3 + (act ? dtw_v * (1.f / 3.f) : 0.f)
                                : base2 + (act ? dtw_v * 0.5f : 0.f);
        A2[((size_t)t * NN + m) * KX + n] = (_Float16)a;
    }
}

// ---------------- build cat (transposed, fp16): cat[z][col][node], col=b*72+k1 ----
__global__ __launch_bounds__(256) void build_cat(
    const float* __restrict__ inputs, const float* __restrict__ states,
    const _Float16* __restrict__ rall, _Float16* __restrict__ cat,
    int tbase, int pass2) {
    __shared__ float hs[64][68];
    __shared__ float rs[64][68];
    const int z = blockIdx.z, t = tbase + z;
    const int b = blockIdx.y, nb = blockIdx.x;
    const int tid = threadIdx.x;
    const float* sb = states + ((size_t)t * BB + b) * NH + (size_t)nb * 4096;
    const float4* src = (const float4*)sb;
#pragma unroll
    for (int q = 0; q < 4; ++q) {
        float4 v = src[tid * 4 + q];
        int fi = tid * 16 + q * 4;
        *(float4*)&hs[fi >> 6][fi & 63] = v;
    }
    if (pass2) {
        const _Float16* rb = rall + ((size_t)t * BB + b) * NH + (size_t)nb * 4096;
#pragma unroll
        for (int i = 0; i < 16; ++i) {
            int fi = tid * 16 + i;
            rs[fi >> 6][fi & 63] = (float)rb[fi];
        }
    }
    __syncthreads();
    _Float16* catz = cat + (size_t)z * NC2 * KX;
    int jp = tid >> 2, ni = (tid & 3) << 4;
    int col = b * BPAD + 1 + jp;   // feature k1 = 1 + jp
    __attribute__((aligned(16))) _Float16 hib[16];
#pragma unroll
    for (int i = 0; i < 16; ++i) {
        float v = hs[ni + i][jp];
        if (pass2) v *= rs[ni + i][jp];
        hib[i] = (_Float16)v;
    }
    size_t dst = (size_t)col * KX + nb * 64 + ni;
    *(uint4*)(catz + dst)     = *(uint4*)&hib[0];
    *(uint4*)(catz + dst + 8) = *(uint4*)&hib[8];
    if (tid < 64) {
        float v = inputs[((size_t)b * TT + t) * NN + nb * 64 + tid];
        catz[(size_t)(b * BPAD) * KX + nb * 64 + tid] = (_Float16)v;   // k1 = 0 (x)
    }
}

// ---------------- pass-2 cat update in place (C=12 path): cat *= r ----------
__global__ __launch_bounds__(256) void scale_cat(
    const _Float16* __restrict__ rall, _Float16* __restrict__ cat, int tbase) {
    __shared__ float rs[64][68];    // rs[node][hh]
    const int z = blockIdx.z, t = tbase + z;
    const int b = blockIdx.y, nb = blockIdx.x;
    const int tid = threadIdx.x;
    const _Float16* rb = rall + ((size_t)t * BB + b) * NH + (size_t)nb * 4096;
    {
        h8 r0 = *(const h8*)(rb + tid * 16);
        h8 r1 = *(const h8*)(rb + tid * 16 + 8);
        int node = tid >> 2, c0 = (tid & 3) << 4;
#pragma unroll
        for (int i = 0; i < 8; ++i) {
            rs[node][c0 + i]     = (float)r0[i];
            rs[node][c0 + 8 + i] = (float)r1[i];
        }
    }
    __syncthreads();
    _Float16* catz = cat + (size_t)z * NC2 * KX;
    const int jp = tid >> 2, ni = (tid & 3) << 4;
    const int col = b * BPAD + 1 + jp;
    size_t dst = (size_t)col * KX + nb * 64 + ni;
    h8 v0 = *(const h8*)(catz + dst);
    h8 v1 = *(const h8*)(catz + dst + 8);
    h8 o0, o1;
#pragma unroll
    for (int i = 0; i < 8; ++i) {
        o0[i] = (_Float16)((float)v0[i] * rs[ni + i][jp]);
        o1[i] = (_Float16)((float)v1[i] * rs[ni + 8 + i][jp]);
    }
    *(h8*)(catz + dst)     = o0;
    *(h8*)(catz + dst + 8) = o1;
}

// ---- MFMA GEMM (fp16, K=1024): 128x256 block, 128x64/wave, 2-buf (48KB LDS,
// ---- 3 blocks/CU: grid 864/768 = 1.125 rounds), 32x32x16 MFMA ----
__global__ __launch_bounds__(256, 3) void gemm_f16(
    const _Float16* __restrict__ A2, const _Float16* __restrict__ cat,
    _Float16* __restrict__ P, int tbase) {
    __shared__ __align__(16) _Float16 smem[NBUF * (BM + BN) * BKK];   // 48 KB
    _Float16* Asb = smem;                       // [NBUF][BM*BKK]
    _Float16* Xsb = smem + NBUF * BM * BKK;     // [NBUF][BN*BKK]
    const int tid = threadIdx.x;
    const int lane = tid & 63;
    const int wid = tid >> 6;
    int bid = blockIdx.x;
    int l = (bid & 7) * ((int)gridDim.x >> 3) + (bid >> 3);
    int z = l / 72; int r = l - z * 72;
    int g  = r / 12, w = r - g * 12;
    int gy = g & 1, gx = g >> 1;          // gx in [0,3)
    int by = (gy << 2) + (w & 3);         // 0..7
    int bx = gx * 3 + (w >> 2);           // 0..8
    const int m0 = by * BM;
    const int n0 = bx * BN;
    const _Float16* Ab = A2 + (size_t)(tbase + z) * NN * KX + (size_t)m0 * KX;
    const _Float16* Xb = cat + (size_t)z * NC2 * KX + (size_t)n0 * KX;

    // 4 row-tiles (32 rows) x 2 col-tiles (32 cols) of 32x32 accumulators
    f32x16 acc[4][2];
#pragma unroll
    for (int i = 0; i < 4; ++i)
#pragma unroll
        for (int j = 0; j < 2; ++j)
#pragma unroll
            for (int q = 0; q < 16; ++q) acc[i][j][q] = 0.f;

    const int wn = wid << 6;       // wave's 64-col slice
    const int rl = lane & 31;      // row/col within 32-tile
    const int ko = lane >> 5;      // k-octet selector (0/1)

    auto stage = [&](int buf, int k0) {
#pragma unroll
        for (int c = 0; c < 2; ++c) {
            int p = c * 256 + tid;          // 0..511
            int row = p & 127;
            int kg  = p >> 7;               // 0..3
            gload16(Ab + (size_t)row * KX + k0 + kg * 8, &Asb[(size_t)(buf * BM * BKK + p * 8)]);
        }
#pragma unroll
        for (int c = 0; c < 4; ++c) {
            int p = c * 256 + tid;          // 0..1023
            int row = p & 255;
            int kg  = p >> 8;               // 0..3
            gload16(Xb + (size_t)row * KX + k0 + kg * 8, &Xsb[(size_t)(buf * BN * BKK + p * 8)]);
        }
    };
    auto compute = [&](int buf) {
#pragma unroll
        for (int ks = 0; ks < 2; ++ks) {           // k-halves of the 32-k slab
            const int oct = (ks << 1) + ko;        // octet 0..3 within slab
            h8 a[4], x[2];
#pragma unroll
            for (int i = 0; i < 4; ++i)
                a[i] = *(const h8*)&Asb[(size_t)(buf * BM * BKK + ((oct << 7) + (i << 5) + rl) * 8)];
#pragma unroll
            for (int j = 0; j < 2; ++j)
                x[j] = *(const h8*)&Xsb[(size_t)(buf * BN * BKK + ((oct << 8) + wn + (j << 5) + rl) * 8)];
#pragma unroll
            for (int i = 0; i < 4; ++i)
#pragma unroll
                for (int j = 0; j < 2; ++j)
                    acc[i][j] = __builtin_amdgcn_mfma_f32_32x32x16_f16(a[i], x[j], acc[i][j], 0, 0, 0);
        }
    };

    stage(0, 0);
    stage(1, BKK);
    const int nk = KX / BKK;   // 32
    for (int it = 0; it < nk; ++it) {
        if (it + 1 < nk) {
            // 2 slabs in flight (12 loads/thread); wait oldest 6 -> cur ready
            asm volatile("s_waitcnt vmcnt(6)" ::: "memory");
        } else {
            asm volatile("s_waitcnt vmcnt(0)" ::: "memory");
        }
        __builtin_amdgcn_s_barrier();      // cur fully written (all waves)
        compute(it & 1);
        __builtin_amdgcn_s_barrier();      // all waves done reading cur before re-stage
        if (it + 2 < nk) stage(it & 1, (it + 2) * BKK);
    }

    // ---- epilogue: two 64-row passes through LDS (fits 48KB), uint4 stores ----
    // acc[i][j][reg]: row = i*32 + (reg&3) + 8*(reg>>2) + 4*ko, col = wn + j*32 + rl
    _Float16* Pt = smem;                   // 64 x PTS fp16 = 33 KB per pass
    _Float16* Pz = P + (size_t)z * NN * NC2;
#pragma unroll
    for (int h = 0; h < 2; ++h) {
        if (h) __syncthreads();            // pass-0 reads done before overwrite
#pragma unroll
        for (int i2 = 0; i2 < 2; ++i2) {   // acc row-tiles 2h, 2h+1
            const int i = (h << 1) + i2;
#pragma unroll
            for (int j = 0; j < 2; ++j)
#pragma unroll
                for (int q = 0; q < 16; ++q) {
                    int row = (i2 << 5) + (q & 3) + ((q >> 2) << 3) + (ko << 2);
                    Pt[row * PTS + wn + (j << 5) + rl] = (_Float16)acc[i][j][q];
                }
        }
        __syncthreads();
#pragma unroll
        for (int c = 0; c < 8; ++c) {
            int u = c * 256 + tid;          // 0..2047
            int rr = u >> 5;                // 0..63
            int cc = u & 31;                // 0..31
            uint4 v = *(const uint4*)&Pt[rr * PTS + cc * 8];
            *(uint4*)(Pz + (size_t)(m0 + (h << 6) + rr) * NC2 + n0 + cc * 8) = v;
        }
    }
}

// ---------------- fused pass-1 stage2 (MFMA): prefix over zc t's in AGPRs ----
__global__ __launch_bounds__(256) void stage2m(const _Float16* __restrict__ P,
                                               const float* __restrict__ W,
                                               const float* __restrict__ bias,
                                               float* __restrict__ cum,
                                               _Float16* __restrict__ rall,
                                               int tbase, int zc) {
    __shared__ __align__(16) _Float16 Pl[TT * NC2];   // 55.3 KB
    __shared__ _Float16 Wl[K1 * 128];                 // 16.6 KB
    const int m = blockIdx.x;
    const int tid = threadIdx.x;
    const int lane = tid & 63, wid = tid >> 6;
    const int fl = lane & 15, fh = lane >> 4;
    for (int i = tid; i < K1 * 128; i += 256) Wl[i] = (_Float16)W[i];
    const int chunks = zc * (NC2 / 8);
    for (int idx = tid; idx < chunks; idx += 256) {
        int z = idx / (NC2 / 8), off = idx - z * (NC2 / 8);
        gload16(P + ((size_t)z * NN + m) * NC2 + off * 8, (char*)Pl + (size_t)idx * 16);
    }
    __syncthreads();
    const int nt0 = wid * 2;
    h8 wf[2][2];
    float w64[2], bvv[2];
#pragma unroll
    for (int n2 = 0; n2 < 2; ++n2) {
        int k2 = (nt0 + n2) * 16 + fl;
        w64[n2] = (float)Wl[64 * 128 + k2];
        bvv[n2] = bias[k2];
#pragma unroll
        for (int ks = 0; ks < 2; ++ks) {
            h8 tmp;
#pragma unroll
            for (int j = 0; j < 8; ++j)
                tmp[j] = Wl[(ks * 32 + fh * 8 + j) * 128 + k2];
            wf[n2][ks] = tmp;
        }
    }
    f32x4 g[2][2];
    if (tbase > 0) {
#pragma unroll
        for (int mt = 0; mt < 2; ++mt)
#pragma unroll
            for (int n2 = 0; n2 < 2; ++n2)
#pragma unroll
                for (int r4 = 0; r4 < 4; ++r4) {
                    int b = mt * 16 + fh * 4 + r4;
                    int k2 = (nt0 + n2) * 16 + fl;
                    g[mt][n2][r4] = cum[(size_t)b * (2 * NH) + (size_t)m * 128 + k2];
                }
    } else {
#pragma unroll
        for (int mt = 0; mt < 2; ++mt)
#pragma unroll
            for (int n2 = 0; n2 < 2; ++n2)
                g[mt][n2] = {0.f, 0.f, 0.f, 0.f};
    }
#pragma unroll 1
    for (int z = 0; z < zc; ++z) {
        const _Float16* Pz = &Pl[z * NC2];
        h8 af[2][2];
#pragma unroll
        for (int mt = 0; mt < 2; ++mt)
#pragma unroll
            for (int ks = 0; ks < 2; ++ks)
                af[mt][ks] = *(const h8*)&Pz[(mt * 16 + fl) * BPAD + ks * 32 + fh * 8];
#pragma unroll
        for (int mt = 0; mt < 2; ++mt)
#pragma unroll
            for (int n2 = 0; n2 < 2; ++n2)
#pragma unroll
                for (int ks = 0; ks < 2; ++ks)
                    g[mt][n2] = __builtin_amdgcn_mfma_f32_16x16x32_f16(
                        af[mt][ks], wf[n2][ks], g[mt][n2], 0, 0, 0);
        float p64[2][4];
#pragma unroll
        for (int mt = 0; mt < 2; ++mt)
#pragma unroll
            for (int r4 = 0; r4 < 4; ++r4)
                p64[mt][r4] = (float)Pz[(mt * 16 + fh * 4 + r4) * BPAD + 64];
#pragma unroll
        for (int mt = 0; mt < 2; ++mt)
#pragma unroll
            for (int n2 = 0; n2 < 2; ++n2)
#pragma unroll
                for (int r4 = 0; r4 < 4; ++r4)
                    g[mt][n2][r4] += p64[mt][r4] * w64[n2] + bvv[n2];
        if (m < 512) {   // r-half: f = m*128 + k2 < NH
            const int t = tbase + z;
#pragma unroll
            for (int mt = 0; mt < 2; ++mt)
#pragma unroll
                for (int n2 = 0; n2 < 2; ++n2)
#pragma unroll
                    for (int r4 = 0; r4 < 4; ++r4) {
                        int b = mt * 16 + fh * 4 + r4;
                        int k2 = (nt0 + n2) * 16 + fl;
                        float rv = 1.f / (1.f + expf(-g[mt][n2][r4]));
                        rall[((size_t)t * BB + b) * NH + (size_t)m * 128 + k2] = (_Float16)rv;
                    }
        }
    }
    if (m >= 512 || tbase + zc < TT) {
#pragma unroll
        for (int mt = 0; mt < 2; ++mt)
#pragma unroll
            for (int n2 = 0; n2 < 2; ++n2)
#pragma unroll
                for (int r4 = 0; r4 < 4; ++r4) {
                    int b = mt * 16 + fh * 4 + r4;
                    int k2 = (nt0 + n2) * 16 + fl;
                    cum[(size_t)b * (2 * NH) + (size_t)m * 128 + k2] = g[mt][n2][r4];
                }
    }
}

// ------- pass-2 stage2 fused w/ finalize (C=12): gcn2 = sumP@W2 + 12*b2 -> out -------
__global__ __launch_bounds__(128) void stage2p2f(const _Float16* __restrict__ P,
                                                 const float* __restrict__ W,
                                                 const float* __restrict__ bias,
                                                 const float* __restrict__ cum1,
                                                 const float* __restrict__ states,
                                                 float* __restrict__ out, int zc) {
    __shared__ float Pl[K1][37];
    __shared__ float Wl[K1 * 64];
    const int m = blockIdx.x;
    for (int i = threadIdx.x; i < K1 * 64; i += 128) Wl[i] = W[i];
    for (int i = threadIdx.x; i < NCOLS; i += 128) {
        int b = i / K1, k = i - b * K1;
        float s = 0.f;
        for (int z = 0; z < zc; ++z)
            s += (float)P[((size_t)z * NN + m) * NC2 + b * BPAD + k];
        Pl[k][b] = s;
    }
    __syncthreads();
    const int k2q = (threadIdx.x & 15) << 2;   // 0..60
    const int bq4 = (threadIdx.x >> 4) << 2;   // 0,4,..,28
    const float4 bv = *(const float4*)(bias + k2q);

    for (int bi = 0; bi < 4; ++bi) {
        const int b = bq4 + bi;
        float a0 = 0.f, a1 = 0.f, a2 = 0.f, a3 = 0.f;
#pragma unroll 4
        for (int k = 0; k < K1; ++k) {
            float p = Pl[k][b];
            float4 w4 = *(const float4*)&Wl[k * 64 + k2q];
            a0 += p * w4.x; a1 += p * w4.y; a2 += p * w4.z; a3 += p * w4.w;
        }
        const int f = m * HH + k2q;
        float g0 = a0 + zc * bv.x, g1 = a1 + zc * bv.y;
        float g2 = a2 + zc * bv.z, g3 = a3 + zc * bv.w;
        const float4 ul = *(const float4*)(cum1 + (size_t)b * 2 * NH + NH + f);
        const float4 hv = *(const float4*)(states + ((size_t)(TT - 1) * BB + b) * NH + f);
        float4 ov;
        { float u = 1.f / (1.f + expf(-ul.x)); ov.x = u * hv.x + (1.f - u) * tanhf(g0); }
        { float u = 1.f / (1.f + expf(-ul.y)); ov.y = u * hv.y + (1.f - u) * tanhf(g1); }
        { float u = 1.f / (1.f + expf(-ul.z)); ov.z = u * hv.z + (1.f - u) * tanhf(g2); }
        { float u = 1.f / (1.f + expf(-ul.w)); ov.w = u * hv.w + (1.f - u) * tanhf(g3); }
        *(float4*)(out + (size_t)b * NH + f) = ov;
        *(float4*)(out + (size_t)BB * NH + (size_t)b * NH + f) = ov;
    }
}

// ---------------- fallback pass-2 stage2 (+ separate finalize) ------
__global__ __launch_bounds__(128) void stage2p2(const _Float16* __restrict__ P,
                                                const float* __restrict__ W,
                                                const float* __restrict__ bias,
                                                float* __restrict__ cum, int zc) {
    __shared__ float Pl[K1][37];
    __shared__ float Wl[K1 * 64];
    const int m = blockIdx.x;
    for (int i = threadIdx.x; i < K1 * 64; i += 128) Wl[i] = W[i];
    for (int i = threadIdx.x; i < NCOLS; i += 128) {
        int b = i / K1, k = i - b * K1;
        float s = 0.f;
        for (int z = 0; z < zc; ++z)
            s += (float)P[((size_t)z * NN + m) * NC2 + b * BPAD + k];
        Pl[k][b] = s;
    }
    __syncthreads();
    const int k2q = (threadIdx.x & 15) << 2;
    const int bq4 = (threadIdx.x >> 4) << 2;
    const float4 bv = *(const float4*)(bias + k2q);

    for (int bi = 0; bi < 4; ++bi) {
        const int b = bq4 + bi;
        float a0 = 0.f, a1 = 0.f, a2 = 0.f, a3 = 0.f;
#pragma unroll 4
        for (int k = 0; k < K1; ++k) {
            float p = Pl[k][b];
            float4 w4 = *(const float4*)&Wl[k * 64 + k2q];
            a0 += p * w4.x; a1 += p * w4.y; a2 += p * w4.z; a3 += p * w4.w;
        }
        float* cp = cum + (size_t)b * NN * 64 + (size_t)m * 64 + k2q;
        float4 c4 = *(float4*)cp;
        c4.x += a0 + zc * bv.x; c4.y += a1 + zc * bv.y;
        c4.z += a2 + zc * bv.z; c4.w += a3 + zc * bv.w;
        *(float4*)cp = c4;
    }
}

__global__ void finalize(const float* __restrict__ cum1, const float* __restrict__ cum2,
                         const float* __restrict__ states, float* __restrict__ out) {
    int idx = blockIdx.x * blockDim.x + threadIdx.x;
    if (idx >= BB * NH) return;
    int b = idx >> 16;
    int f = idx & (NH - 1);
    float u = 1.f / (1.f + expf(-cum1[(size_t)b * 2 * NH + NH + f]));
    float h = states[((size_t)(TT - 1) * BB + b) * NH + f];
    float c = tanhf(cum2[idx]);
    float o = u * h + (1.f - u) * c;
    out[idx] = o;
    out[(size_t)BB * NH + idx] = o;
}

extern "C" void kernel_launch(void* const* d_in, const int* in_sizes, int n_in,
                              void* d_out, int out_size, void* d_ws, size_t ws_size,
                              hipStream_t stream) {
    const float* inputs = (const float*)d_in[0];
    const float* states = (const float*)d_in[1];
    const float* dtw    = (const float*)d_in[2];
    const float* adj    = (const float*)d_in[3];
    const float* spec   = (const float*)d_in[4];
    const float* td     = (const float*)d_in[5];
    const float* W1     = (const float*)d_in[6];
    const float* b1     = (const float*)d_in[7];
    const float* W2     = (const float*)d_in[8];
    const float* b2     = (const float*)d_in[9];
    const int*   sr     = (const int*)d_in[10];
    float* out = (float*)d_out;

    char* ws = (char*)d_ws;
    const size_t szA2   = (size_t)TT * NN * KX * 2;     // 25.2 MB
    const size_t szCum1 = (size_t)BB * 2 * NH * 4;      // 16.8 MB
    const size_t szCum2 = (size_t)BB * NH * 4;          // 8.4 MB
    const size_t szRall = (size_t)TT * BB * NH * 2;     // 50.3 MB

    _Float16* A2  = (_Float16*)ws;
    float* cum1 = (float*)(ws + szA2);
    float* cum2 = (float*)(ws + szA2 + szCum1);
    float* dsA  = (float*)(ws + szA2 + szCum1 + szCum2);
    float* dsS  = (float*)(ws + szA2 + szCum1 + szCum2 + 4096);
    _Float16* rall = (_Float16*)(ws + szA2 + szCum1 + szCum2 + 8192);
    size_t offRest = szA2 + szCum1 + szCum2 + 8192 + szRall;

    rowsum_rsqrt2<<<2 * NN, 256, 0, stream>>>(adj, spec, dsA, dsS);
    build_A2<<<(NN * NN) / 256, 256, 0, stream>>>(dtw, adj, spec, td, dsA, dsS, sr, A2);

    const size_t szCatZ = (size_t)NC2 * KX * 2;         // 4.72 MB per t
    const size_t szPZ   = (size_t)NN * NC2 * 2;         // 4.72 MB per t
    int C;
    if      (ws_size >= offRest + 12 * (szCatZ + szPZ)) C = 12;
    else if (ws_size >= offRest + 4 * (szCatZ + szPZ))  C = 4;
    else                                                C = 1;
    _Float16* cat = (_Float16*)(ws + offRest);
    _Float16* P16 = (_Float16*)(ws + offRest + (size_t)C * szCatZ);

    if (C == 12) {
        // pass 1
        build_cat<<<dim3(16, 32, 12), 256, 0, stream>>>(inputs, states, nullptr, cat, 0, 0);
        gemm_f16<<<dim3(72 * 12), 256, 0, stream>>>(A2, cat, P16, 0);
        stage2m<<<NN, 256, 0, stream>>>(P16, W1, b1, cum1, rall, 0, 12);
        // pass 2: scale cat in place, gemm, fused stage2+finalize
        scale_cat<<<dim3(16, 32, 12), 256, 0, stream>>>(rall, cat, 0);
        gemm_f16<<<dim3(72 * 12), 256, 0, stream>>>(A2, cat, P16, 0);
        stage2p2f<<<NN, 128, 0, stream>>>(P16, W2, b2, cum1, states, out, 12);
    } else {
        hipMemsetAsync(cum2, 0, szCum2, stream);
        for (int tb = 0; tb < TT; tb += C) {
            build_cat<<<dim3(16, 32, C), 256, 0, stream>>>(inputs, states, nullptr, cat, tb, 0);
            gemm_f16<<<dim3(72 * C), 256, 0, stream>>>(A2, cat, P16, tb);
            stage2m<<<NN, 256, 0, stream>>>(P16, W1, b1, cum1, rall, tb, C);
        }
        for (int tb = 0; tb < TT; tb += C) {
            build_cat<<<dim3(16, 32, C), 256, 0, stream>>>(inputs, states, rall, cat, tb, 1);
            gemm_f16<<<dim3(72 * C), 256, 0, stream>>>(A2, cat, P16, tb);
            stage2p2<<<NN, 128, 0, stream>>>(P16, W2, b2, cum2, C);
        }
        finalize<<<(BB * NH + 255) / 256, 256, 0, stream>>>(cum1, cum2, states, out);
    }
}

// Round 18
// 355.339 us; speedup vs baseline: 1.2052x; 1.1132x over previous
//
#include <hip/hip_runtime.h>
#include <math.h>

#define NN 1024
#define BB 32
#define TT 12
#define HH 64
#define K1 65
#define NCOLS (BB * K1)   // 2080 valid columns
#define BPAD 72           // per-b column stride (16B-aligned fp16 rows)
#define NC2 (BB * BPAD)   // 2304 = 18*128
#define NH (NN * HH)      // 65536
#define KX 1024           // K: fp16 (A and X)
#define BM 128
#define BN 256
#define BKK 32
#define NBUF 2
#define PTS 264           // epilogue LDS tile stride (f16)

typedef __attribute__((ext_vector_type(8))) _Float16 h8;
typedef __attribute__((ext_vector_type(4))) float f32x4;
typedef __attribute__((ext_vector_type(16))) float f32x16;

__device__ __forceinline__ void gload16(const void* g, void* l) {
    __builtin_amdgcn_global_load_lds((__attribute__((address_space(1))) void*)g,
                                     (__attribute__((address_space(3))) void*)l,
                                     16, 0, 0);
}

// ---------------- row-sum -> d^{-1/2} (both matrices in one launch) ----------
__global__ void rowsum_rsqrt2(const float* __restrict__ M0, const float* __restrict__ M1,
                              float* __restrict__ ds0, float* __restrict__ ds1) {
    int bid = blockIdx.x;
    const float* p = (bid < NN ? M0 : M1) + (size_t)(bid & (NN - 1)) * NN;
    float* ds = (bid < NN ? ds0 : ds1) + (bid & (NN - 1));
    float s = 0.f;
    for (int i = threadIdx.x; i < NN; i += blockDim.x) s += p[i];
    __shared__ float red[256];
    red[threadIdx.x] = s;
    __syncthreads();
    for (int off = 128; off; off >>= 1) {
        if (threadIdx.x < off) red[threadIdx.x] += red[threadIdx.x + off];
        __syncthreads();
    }
    if (threadIdx.x == 0) {
        float d = red[0];
        *ds = d > 0.f ? 1.0f / sqrtf(d) : 0.f;
    }
}

// ---------------- build A_t fp16: A2[t][m][n] ----------------
__global__ void build_A2(const float* __restrict__ dtw, const float* __restrict__ adj,
                         const float* __restrict__ spec, const float* __restrict__ td,
                         const float* __restrict__ dsA, const float* __restrict__ dsS,
                         const int* __restrict__ sr_ptr, _Float16* __restrict__ A2) {
    int idx = blockIdx.x * blockDim.x + threadIdx.x;
    int m = idx >> 10, n = idx & 1023;
    float sr = (float)sr_ptr[0];
    float dtw_v = dtw[idx], adj_v = adj[idx], spec_v = spec[idx], td_v = td[idx];
    float I = (m == n) ? 1.f : 0.f;
    float Lspec = I - dsS[m] * spec_v * dsS[n];
    float Ladj  = I - dsA[m] * adj_v * dsA[n];
    float tind = (float)TT - ceilf(fabsf(td_v) / sr);
    float base2 = 0.5f * (Lspec + I);
    float base3 = (Lspec + Ladj + I) * (1.f / 3.f);
    bool nz = (dtw_v != 0.f);
#pragma unroll
    for (int t = 0; t < TT; ++t) {
        bool act = nz && ((float)(t + 1) > tind);
        float a = (t == TT - 1) ? base3 + (act ? dtw_v * (1.f / 3.f) : 0.f)
                                : base2 + (act ? dtw_v * 0.5f : 0.f);
        A2[((size_t)t * NN + m) * KX + n] = (_Float16)a;
    }
}

// ---------------- build cat (transposed, fp16): cat[z][col][node], col=b*72+k1 ----
__global__ __launch_bounds__(256) void build_cat(
    const float* __restrict__ inputs, const float* __restrict__ states,
    const _Float16* __restrict__ rall, _Float16* __restrict__ cat,
    int tbase, int pass2) {
    __shared__ float hs[64][68];
    __shared__ float rs[64][68];
    const int z = blockIdx.z, t = tbase + z;
    const int b = blockIdx.y, nb = blockIdx.x;
    const int tid = threadIdx.x;
    const float* sb = states + ((size_t)t * BB + b) * NH + (size_t)nb * 4096;
    const float4* src = (const float4*)sb;
#pragma unroll
    for (int q = 0; q < 4; ++q) {
        float4 v = src[tid * 4 + q];
        int fi = tid * 16 + q * 4;
        *(float4*)&hs[fi >> 6][fi & 63] = v;
    }
    if (pass2) {
        const _Float16* rb = rall + ((size_t)t * BB + b) * NH + (size_t)nb * 4096;
#pragma unroll
        for (int i = 0; i < 16; ++i) {
            int fi = tid * 16 + i;
            rs[fi >> 6][fi & 63] = (float)rb[fi];
        }
    }
    __syncthreads();
    _Float16* catz = cat + (size_t)z * NC2 * KX;
    int jp = tid >> 2, ni = (tid & 3) << 4;
    int col = b * BPAD + 1 + jp;   // feature k1 = 1 + jp
    __attribute__((aligned(16))) _Float16 hib[16];
#pragma unroll
    for (int i = 0; i < 16; ++i) {
        float v = hs[ni + i][jp];
        if (pass2) v *= rs[ni + i][jp];
        hib[i] = (_Float16)v;
    }
    size_t dst = (size_t)col * KX + nb * 64 + ni;
    *(uint4*)(catz + dst)     = *(uint4*)&hib[0];
    *(uint4*)(catz + dst + 8) = *(uint4*)&hib[8];
    if (tid < 64) {
        float v = inputs[((size_t)b * TT + t) * NN + nb * 64 + tid];
        catz[(size_t)(b * BPAD) * KX + nb * 64 + tid] = (_Float16)v;   // k1 = 0 (x)
    }
}

// ---------------- pass-2 cat update in place (C=12 path): cat *= r ----------
__global__ __launch_bounds__(256) void scale_cat(
    const _Float16* __restrict__ rall, _Float16* __restrict__ cat, int tbase) {
    __shared__ float rs[64][68];    // rs[node][hh]
    const int z = blockIdx.z, t = tbase + z;
    const int b = blockIdx.y, nb = blockIdx.x;
    const int tid = threadIdx.x;
    const _Float16* rb = rall + ((size_t)t * BB + b) * NH + (size_t)nb * 4096;
    {
        h8 r0 = *(const h8*)(rb + tid * 16);
        h8 r1 = *(const h8*)(rb + tid * 16 + 8);
        int node = tid >> 2, c0 = (tid & 3) << 4;
#pragma unroll
        for (int i = 0; i < 8; ++i) {
            rs[node][c0 + i]     = (float)r0[i];
            rs[node][c0 + 8 + i] = (float)r1[i];
        }
    }
    __syncthreads();
    _Float16* catz = cat + (size_t)z * NC2 * KX;
    const int jp = tid >> 2, ni = (tid & 3) << 4;
    const int col = b * BPAD + 1 + jp;
    size_t dst = (size_t)col * KX + nb * 64 + ni;
    h8 v0 = *(const h8*)(catz + dst);
    h8 v1 = *(const h8*)(catz + dst + 8);
    h8 o0, o1;
#pragma unroll
    for (int i = 0; i < 8; ++i) {
        o0[i] = (_Float16)((float)v0[i] * rs[ni + i][jp]);
        o1[i] = (_Float16)((float)v1[i] * rs[ni + 8 + i][jp]);
    }
    *(h8*)(catz + dst)     = o0;
    *(h8*)(catz + dst + 8) = o1;
}

// ---- MFMA GEMM (fp16, K=1024): 128x256 block, 128x64/wave, 2-buf (48KB LDS,
// ---- 3 blocks/CU), 32x32x16 MFMA — pinned config (r15/r17, 123 us) ----
__global__ __launch_bounds__(256, 3) void gemm_f16(
    const _Float16* __restrict__ A2, const _Float16* __restrict__ cat,
    _Float16* __restrict__ P, int tbase) {
    __shared__ __align__(16) _Float16 smem[NBUF * (BM + BN) * BKK];   // 48 KB
    _Float16* Asb = smem;                       // [NBUF][BM*BKK]
    _Float16* Xsb = smem + NBUF * BM * BKK;     // [NBUF][BN*BKK]
    const int tid = threadIdx.x;
    const int lane = tid & 63;
    const int wid = tid >> 6;
    int bid = blockIdx.x;
    int l = (bid & 7) * ((int)gridDim.x >> 3) + (bid >> 3);
    int z = l / 72; int r = l - z * 72;
    int g  = r / 12, w = r - g * 12;
    int gy = g & 1, gx = g >> 1;          // gx in [0,3)
    int by = (gy << 2) + (w & 3);         // 0..7
    int bx = gx * 3 + (w >> 2);           // 0..8
    const int m0 = by * BM;
    const int n0 = bx * BN;
    const _Float16* Ab = A2 + (size_t)(tbase + z) * NN * KX + (size_t)m0 * KX;
    const _Float16* Xb = cat + (size_t)z * NC2 * KX + (size_t)n0 * KX;

    f32x16 acc[4][2];
#pragma unroll
    for (int i = 0; i < 4; ++i)
#pragma unroll
        for (int j = 0; j < 2; ++j)
#pragma unroll
            for (int q = 0; q < 16; ++q) acc[i][j][q] = 0.f;

    const int wn = wid << 6;       // wave's 64-col slice
    const int rl = lane & 31;      // row/col within 32-tile
    const int ko = lane >> 5;      // k-octet selector (0/1)

    auto stage = [&](int buf, int k0) {
#pragma unroll
        for (int c = 0; c < 2; ++c) {
            int p = c * 256 + tid;          // 0..511
            int row = p & 127;
            int kg  = p >> 7;               // 0..3
            gload16(Ab + (size_t)row * KX + k0 + kg * 8, &Asb[(size_t)(buf * BM * BKK + p * 8)]);
        }
#pragma unroll
        for (int c = 0; c < 4; ++c) {
            int p = c * 256 + tid;          // 0..1023
            int row = p & 255;
            int kg  = p >> 8;               // 0..3
            gload16(Xb + (size_t)row * KX + k0 + kg * 8, &Xsb[(size_t)(buf * BN * BKK + p * 8)]);
        }
    };
    auto compute = [&](int buf) {
#pragma unroll
        for (int ks = 0; ks < 2; ++ks) {           // k-halves of the 32-k slab
            const int oct = (ks << 1) + ko;        // octet 0..3 within slab
            h8 a[4], x[2];
#pragma unroll
            for (int i = 0; i < 4; ++i)
                a[i] = *(const h8*)&Asb[(size_t)(buf * BM * BKK + ((oct << 7) + (i << 5) + rl) * 8)];
#pragma unroll
            for (int j = 0; j < 2; ++j)
                x[j] = *(const h8*)&Xsb[(size_t)(buf * BN * BKK + ((oct << 8) + wn + (j << 5) + rl) * 8)];
#pragma unroll
            for (int i = 0; i < 4; ++i)
#pragma unroll
                for (int j = 0; j < 2; ++j)
                    acc[i][j] = __builtin_amdgcn_mfma_f32_32x32x16_f16(a[i], x[j], acc[i][j], 0, 0, 0);
        }
    };

    stage(0, 0);
    stage(1, BKK);
    const int nk = KX / BKK;   // 32
    for (int it = 0; it < nk; ++it) {
        if (it + 1 < nk) {
            asm volatile("s_waitcnt vmcnt(6)" ::: "memory");
        } else {
            asm volatile("s_waitcnt vmcnt(0)" ::: "memory");
        }
        __builtin_amdgcn_s_barrier();      // cur fully written (all waves)
        compute(it & 1);
        __builtin_amdgcn_s_barrier();      // all waves done reading cur before re-stage
        if (it + 2 < nk) stage(it & 1, (it + 2) * BKK);
    }

    // ---- epilogue: two 64-row passes through LDS (fits 48KB), uint4 stores ----
    _Float16* Pt = smem;                   // 64 x PTS fp16 = 33 KB per pass
    _Float16* Pz = P + (size_t)z * NN * NC2;
#pragma unroll
    for (int h = 0; h < 2; ++h) {
        if (h) __syncthreads();            // pass-0 reads done before overwrite
#pragma unroll
        for (int i2 = 0; i2 < 2; ++i2) {   // acc row-tiles 2h, 2h+1
            const int i = (h << 1) + i2;
#pragma unroll
            for (int j = 0; j < 2; ++j)
#pragma unroll
                for (int q = 0; q < 16; ++q) {
                    int row = (i2 << 5) + (q & 3) + ((q >> 2) << 3) + (ko << 2);
                    Pt[row * PTS + wn + (j << 5) + rl] = (_Float16)acc[i][j][q];
                }
        }
        __syncthreads();
#pragma unroll
        for (int c = 0; c < 8; ++c) {
            int u = c * 256 + tid;          // 0..2047
            int rr = u >> 5;                // 0..63
            int cc = u & 31;                // 0..31
            uint4 v = *(const uint4*)&Pt[rr * PTS + cc * 8];
            *(uint4*)(Pz + (size_t)(m0 + (h << 6) + rr) * NC2 + n0 + cc * 8) = v;
        }
    }
}

// ---------------- fused pass-1 stage2 (MFMA): prefix over zc t's in AGPRs ----
// rall writes now staged through LDS (coalesced uint4), fixing scalar 2B stores.
__global__ __launch_bounds__(256) void stage2m(const _Float16* __restrict__ P,
                                               const float* __restrict__ W,
                                               const float* __restrict__ bias,
                                               float* __restrict__ cum,
                                               _Float16* __restrict__ rall,
                                               int tbase, int zc) {
    __shared__ __align__(16) _Float16 Pl[TT * NC2];   // 55.3 KB
    __shared__ _Float16 Wl[K1 * 128];                 // 16.6 KB
    __shared__ __align__(16) _Float16 Rl[BB * 128];   // 8 KB r staging
    const int m = blockIdx.x;
    const int tid = threadIdx.x;
    const int lane = tid & 63, wid = tid >> 6;
    const int fl = lane & 15, fh = lane >> 4;
    for (int i = tid; i < K1 * 128; i += 256) Wl[i] = (_Float16)W[i];
    const int chunks = zc * (NC2 / 8);
    for (int idx = tid; idx < chunks; idx += 256) {
        int z = idx / (NC2 / 8), off = idx - z * (NC2 / 8);
        gload16(P + ((size_t)z * NN + m) * NC2 + off * 8, (char*)Pl + (size_t)idx * 16);
    }
    __syncthreads();
    const int nt0 = wid * 2;
    h8 wf[2][2];
    float w64[2], bvv[2];
#pragma unroll
    for (int n2 = 0; n2 < 2; ++n2) {
        int k2 = (nt0 + n2) * 16 + fl;
        w64[n2] = (float)Wl[64 * 128 + k2];
        bvv[n2] = bias[k2];
#pragma unroll
        for (int ks = 0; ks < 2; ++ks) {
            h8 tmp;
#pragma unroll
            for (int j = 0; j < 8; ++j)
                tmp[j] = Wl[(ks * 32 + fh * 8 + j) * 128 + k2];
            wf[n2][ks] = tmp;
        }
    }
    f32x4 g[2][2];
    if (tbase > 0) {
#pragma unroll
        for (int mt = 0; mt < 2; ++mt)
#pragma unroll
            for (int n2 = 0; n2 < 2; ++n2)
#pragma unroll
                for (int r4 = 0; r4 < 4; ++r4) {
                    int b = mt * 16 + fh * 4 + r4;
                    int k2 = (nt0 + n2) * 16 + fl;
                    g[mt][n2][r4] = cum[(size_t)b * (2 * NH) + (size_t)m * 128 + k2];
                }
    } else {
#pragma unroll
        for (int mt = 0; mt < 2; ++mt)
#pragma unroll
            for (int n2 = 0; n2 < 2; ++n2)
                g[mt][n2] = {0.f, 0.f, 0.f, 0.f};
    }
#pragma unroll 1
    for (int z = 0; z < zc; ++z) {
        const _Float16* Pz = &Pl[z * NC2];
        h8 af[2][2];
#pragma unroll
        for (int mt = 0; mt < 2; ++mt)
#pragma unroll
            for (int ks = 0; ks < 2; ++ks)
                af[mt][ks] = *(const h8*)&Pz[(mt * 16 + fl) * BPAD + ks * 32 + fh * 8];
#pragma unroll
        for (int mt = 0; mt < 2; ++mt)
#pragma unroll
            for (int n2 = 0; n2 < 2; ++n2)
#pragma unroll
                for (int ks = 0; ks < 2; ++ks)
                    g[mt][n2] = __builtin_amdgcn_mfma_f32_16x16x32_f16(
                        af[mt][ks], wf[n2][ks], g[mt][n2], 0, 0, 0);
        float p64[2][4];
#pragma unroll
        for (int mt = 0; mt < 2; ++mt)
#pragma unroll
            for (int r4 = 0; r4 < 4; ++r4)
                p64[mt][r4] = (float)Pz[(mt * 16 + fh * 4 + r4) * BPAD + 64];
#pragma unroll
        for (int mt = 0; mt < 2; ++mt)
#pragma unroll
            for (int n2 = 0; n2 < 2; ++n2)
#pragma unroll
                for (int r4 = 0; r4 < 4; ++r4)
                    g[mt][n2][r4] += p64[mt][r4] * w64[n2] + bvv[n2];
        if (m < 512) {   // r-half: f = m*128 + k2 < NH
            const int t = tbase + z;
#pragma unroll
            for (int mt = 0; mt < 2; ++mt)
#pragma unroll
                for (int n2 = 0; n2 < 2; ++n2)
#pragma unroll
                    for (int r4 = 0; r4 < 4; ++r4) {
                        int b = mt * 16 + fh * 4 + r4;
                        int k2 = (nt0 + n2) * 16 + fl;
                        Rl[b * 128 + k2] = (_Float16)(1.f / (1.f + expf(-g[mt][n2][r4])));
                    }
            __syncthreads();
            // coalesced dump: 32 b x 128 k2 as uint4 (8 fp16), 2 stores/thread
#pragma unroll
            for (int c = 0; c < 2; ++c) {
                int u = c * 256 + tid;      // 0..511
                int b = u >> 4;             // 0..31
                int k2q = (u & 15) << 3;    // 0..120 step 8
                uint4 v = *(const uint4*)&Rl[b * 128 + k2q];
                *(uint4*)(rall + ((size_t)t * BB + b) * NH + (size_t)m * 128 + k2q) = v;
            }
            __syncthreads();   // Rl reuse safe for next z
        }
    }
    if (m >= 512 || tbase + zc < TT) {
#pragma unroll
        for (int mt = 0; mt < 2; ++mt)
#pragma unroll
            for (int n2 = 0; n2 < 2; ++n2)
#pragma unroll
                for (int r4 = 0; r4 < 4; ++r4) {
                    int b = mt * 16 + fh * 4 + r4;
                    int k2 = (nt0 + n2) * 16 + fl;
                    cum[(size_t)b * (2 * NH) + (size_t)m * 128 + k2] = g[mt][n2][r4];
                }
    }
}

// ------- pass-2 stage2 fused w/ finalize (C=12): gcn2 = sumP@W2 + 12*b2 -> out -------
// P-sum now h8-vectorized in registers (z ascending fp32, same order as before).
__global__ __launch_bounds__(128) void stage2p2f(const _Float16* __restrict__ P,
                                                 const float* __restrict__ W,
                                                 const float* __restrict__ bias,
                                                 const float* __restrict__ cum1,
                                                 const float* __restrict__ states,
                                                 float* __restrict__ out, int zc) {
    __shared__ float Pl[K1][37];
    __shared__ float Wl[K1 * 64];
    const int m = blockIdx.x;
    for (int i = threadIdx.x; i < K1 * 64; i += 128) Wl[i] = W[i];
    // vectorized z-sum: 288 h8-chunks over 128 threads (<=3 chunks/thread)
    float s[3][8];
#pragma unroll
    for (int c = 0; c < 3; ++c)
#pragma unroll
        for (int q = 0; q < 8; ++q) s[c][q] = 0.f;
    for (int z = 0; z < zc; ++z) {
        const _Float16* Pz = P + ((size_t)z * NN + m) * NC2;
#pragma unroll
        for (int c = 0; c < 3; ++c) {
            int ch = c * 128 + threadIdx.x;
            if (ch < NC2 / 8) {
                h8 v = *(const h8*)(Pz + ch * 8);
#pragma unroll
                for (int q = 0; q < 8; ++q) s[c][q] += (float)v[q];
            }
        }
    }
#pragma unroll
    for (int c = 0; c < 3; ++c) {
        int ch = c * 128 + threadIdx.x;
        if (ch < NC2 / 8) {
#pragma unroll
            for (int q = 0; q < 8; ++q) {
                int col = ch * 8 + q;
                int b = col / BPAD, k = col - b * BPAD;
                if (k < K1) Pl[k][b] = s[c][q];
            }
        }
    }
    __syncthreads();
    const int k2q = (threadIdx.x & 15) << 2;   // 0..60
    const int bq4 = (threadIdx.x >> 4) << 2;   // 0,4,..,28
    const float4 bv = *(const float4*)(bias + k2q);

    for (int bi = 0; bi < 4; ++bi) {
        const int b = bq4 + bi;
        float a0 = 0.f, a1 = 0.f, a2 = 0.f, a3 = 0.f;
#pragma unroll 4
        for (int k = 0; k < K1; ++k) {
            float p = Pl[k][b];
            float4 w4 = *(const float4*)&Wl[k * 64 + k2q];
            a0 += p * w4.x; a1 += p * w4.y; a2 += p * w4.z; a3 += p * w4.w;
        }
        const int f = m * HH + k2q;
        float g0 = a0 + zc * bv.x, g1 = a1 + zc * bv.y;
        float g2 = a2 + zc * bv.z, g3 = a3 + zc * bv.w;
        const float4 ul = *(const float4*)(cum1 + (size_t)b * 2 * NH + NH + f);
        const float4 hv = *(const float4*)(states + ((size_t)(TT - 1) * BB + b) * NH + f);
        float4 ov;
        { float u = 1.f / (1.f + expf(-ul.x)); ov.x = u * hv.x + (1.f - u) * tanhf(g0); }
        { float u = 1.f / (1.f + expf(-ul.y)); ov.y = u * hv.y + (1.f - u) * tanhf(g1); }
        { float u = 1.f / (1.f + expf(-ul.z)); ov.z = u * hv.z + (1.f - u) * tanhf(g2); }
        { float u = 1.f / (1.f + expf(-ul.w)); ov.w = u * hv.w + (1.f - u) * tanhf(g3); }
        *(float4*)(out + (size_t)b * NH + f) = ov;
        *(float4*)(out + (size_t)BB * NH + (size_t)b * NH + f) = ov;
    }
}

// ---------------- fallback pass-2 stage2 (+ separate finalize) ------
__global__ __launch_bounds__(128) void stage2p2(const _Float16* __restrict__ P,
                                                const float* __restrict__ W,
                                                const float* __restrict__ bias,
                                                float* __restrict__ cum, int zc) {
    __shared__ float Pl[K1][37];
    __shared__ float Wl[K1 * 64];
    const int m = blockIdx.x;
    for (int i = threadIdx.x; i < K1 * 64; i += 128) Wl[i] = W[i];
    for (int i = threadIdx.x; i < NCOLS; i += 128) {
        int b = i / K1, k = i - b * K1;
        float s = 0.f;
        for (int z = 0; z < zc; ++z)
            s += (float)P[((size_t)z * NN + m) * NC2 + b * BPAD + k];
        Pl[k][b] = s;
    }
    __syncthreads();
    const int k2q = (threadIdx.x & 15) << 2;
    const int bq4 = (threadIdx.x >> 4) << 2;
    const float4 bv = *(const float4*)(bias + k2q);

    for (int bi = 0; bi < 4; ++bi) {
        const int b = bq4 + bi;
        float a0 = 0.f, a1 = 0.f, a2 = 0.f, a3 = 0.f;
#pragma unroll 4
        for (int k = 0; k < K1; ++k) {
            float p = Pl[k][b];
            float4 w4 = *(const float4*)&Wl[k * 64 + k2q];
            a0 += p * w4.x; a1 += p * w4.y; a2 += p * w4.z; a3 += p * w4.w;
        }
        float* cp = cum + (size_t)b * NN * 64 + (size_t)m * 64 + k2q;
        float4 c4 = *(float4*)cp;
        c4.x += a0 + zc * bv.x; c4.y += a1 + zc * bv.y;
        c4.z += a2 + zc * bv.z; c4.w += a3 + zc * bv.w;
        *(float4*)cp = c4;
    }
}

__global__ void finalize(const float* __restrict__ cum1, const float* __restrict__ cum2,
                         const float* __restrict__ states, float* __restrict__ out) {
    int idx = blockIdx.x * blockDim.x + threadIdx.x;
    if (idx >= BB * NH) return;
    int b = idx >> 16;
    int f = idx & (NH - 1);
    float u = 1.f / (1.f + expf(-cum1[(size_t)b * 2 * NH + NH + f]));
    float h = states[((size_t)(TT - 1) * BB + b) * NH + f];
    float c = tanhf(cum2[idx]);
    float o = u * h + (1.f - u) * c;
    out[idx] = o;
    out[(size_t)BB * NH + idx] = o;
}

extern "C" void kernel_launch(void* const* d_in, const int* in_sizes, int n_in,
                              void* d_out, int out_size, void* d_ws, size_t ws_size,
                              hipStream_t stream) {
    const float* inputs = (const float*)d_in[0];
    const float* states = (const float*)d_in[1];
    const float* dtw    = (const float*)d_in[2];
    const float* adj    = (const float*)d_in[3];
    const float* spec   = (const float*)d_in[4];
    const float* td     = (const float*)d_in[5];
    const float* W1     = (const float*)d_in[6];
    const float* b1     = (const float*)d_in[7];
    const float* W2     = (const float*)d_in[8];
    const float* b2     = (const float*)d_in[9];
    const int*   sr     = (const int*)d_in[10];
    float* out = (float*)d_out;

    char* ws = (char*)d_ws;
    const size_t szA2   = (size_t)TT * NN * KX * 2;     // 25.2 MB
    const size_t szCum1 = (size_t)BB * 2 * NH * 4;      // 16.8 MB
    const size_t szCum2 = (size_t)BB * NH * 4;          // 8.4 MB
    const size_t szRall = (size_t)TT * BB * NH * 2;     // 50.3 MB

    _Float16* A2  = (_Float16*)ws;
    float* cum1 = (float*)(ws + szA2);
    float* cum2 = (float*)(ws + szA2 + szCum1);
    float* dsA  = (float*)(ws + szA2 + szCum1 + szCum2);
    float* dsS  = (float*)(ws + szA2 + szCum1 + szCum2 + 4096);
    _Float16* rall = (_Float16*)(ws + szA2 + szCum1 + szCum2 + 8192);
    size_t offRest = szA2 + szCum1 + szCum2 + 8192 + szRall;

    rowsum_rsqrt2<<<2 * NN, 256, 0, stream>>>(adj, spec, dsA, dsS);
    build_A2<<<(NN * NN) / 256, 256, 0, stream>>>(dtw, adj, spec, td, dsA, dsS, sr, A2);

    const size_t szCatZ = (size_t)NC2 * KX * 2;         // 4.72 MB per t
    const size_t szPZ   = (size_t)NN * NC2 * 2;         // 4.72 MB per t
    int C;
    if      (ws_size >= offRest + 12 * (szCatZ + szPZ)) C = 12;
    else if (ws_size >= offRest + 4 * (szCatZ + szPZ))  C = 4;
    else                                                C = 1;
    _Float16* cat = (_Float16*)(ws + offRest);
    _Float16* P16 = (_Float16*)(ws + offRest + (size_t)C * szCatZ);

    if (C == 12) {
        // pass 1
        build_cat<<<dim3(16, 32, 12), 256, 0, stream>>>(inputs, states, nullptr, cat, 0, 0);
        gemm_f16<<<dim3(72 * 12), 256, 0, stream>>>(A2, cat, P16, 0);
        stage2m<<<NN, 256, 0, stream>>>(P16, W1, b1, cum1, rall, 0, 12);
        // pass 2: scale cat in place, gemm, fused stage2+finalize
        scale_cat<<<dim3(16, 32, 12), 256, 0, stream>>>(rall, cat, 0);
        gemm_f16<<<dim3(72 * 12), 256, 0, stream>>>(A2, cat, P16, 0);
        stage2p2f<<<NN, 128, 0, stream>>>(P16, W2, b2, cum1, states, out, 12);
    } else {
        hipMemsetAsync(cum2, 0, szCum2, stream);
        for (int tb = 0; tb < TT; tb += C) {
            build_cat<<<dim3(16, 32, C), 256, 0, stream>>>(inputs, states, nullptr, cat, tb, 0);
            gemm_f16<<<dim3(72 * C), 256, 0, stream>>>(A2, cat, P16, tb);
            stage2m<<<NN, 256, 0, stream>>>(P16, W1, b1, cum1, rall, tb, C);
        }
        for (int tb = 0; tb < TT; tb += C) {
            build_cat<<<dim3(16, 32, C), 256, 0, stream>>>(inputs, states, rall, cat, tb, 1);
            gemm_f16<<<dim3(72 * C), 256, 0, stream>>>(A2, cat, P16, tb);
            stage2p2<<<NN, 128, 0, stream>>>(P16, W2, b2, cum2, C);
        }
        finalize<<<(BB * NH + 255) / 256, 256, 0, stream>>>(cum1, cum2, states, out);
    }
}

// Round 19
// 354.500 us; speedup vs baseline: 1.2081x; 1.0024x over previous
//
#include <hip/hip_runtime.h>
#include <math.h>

#define NN 1024
#define BB 32
#define TT 12
#define HH 64
#define K1 65
#define NCOLS (BB * K1)   // 2080 valid columns
#define BPAD 72           // per-b column stride (16B-aligned fp16 rows)
#define NC2 (BB * BPAD)   // 2304 = 18*128
#define NH (NN * HH)      // 65536
#define KX 1024           // K: fp16 (A and X)
#define BM 128
#define BN 256
#define BKK 32
#define NBUF 2
#define PTS 264           // epilogue LDS tile stride (f16)

typedef __attribute__((ext_vector_type(8))) _Float16 h8;
typedef __attribute__((ext_vector_type(4))) float f32x4;
typedef __attribute__((ext_vector_type(16))) float f32x16;

__device__ __forceinline__ void gload16(const void* g, void* l) {
    __builtin_amdgcn_global_load_lds((__attribute__((address_space(1))) void*)g,
                                     (__attribute__((address_space(3))) void*)l,
                                     16, 0, 0);
}

// ---------------- row-sum -> d^{-1/2} (both matrices in one launch) ----------
__global__ void rowsum_rsqrt2(const float* __restrict__ M0, const float* __restrict__ M1,
                              float* __restrict__ ds0, float* __restrict__ ds1) {
    int bid = blockIdx.x;
    const float* p = (bid < NN ? M0 : M1) + (size_t)(bid & (NN - 1)) * NN;
    float* ds = (bid < NN ? ds0 : ds1) + (bid & (NN - 1));
    float s = 0.f;
    for (int i = threadIdx.x; i < NN; i += blockDim.x) s += p[i];
    __shared__ float red[256];
    red[threadIdx.x] = s;
    __syncthreads();
    for (int off = 128; off; off >>= 1) {
        if (threadIdx.x < off) red[threadIdx.x] += red[threadIdx.x + off];
        __syncthreads();
    }
    if (threadIdx.x == 0) {
        float d = red[0];
        *ds = d > 0.f ? 1.0f / sqrtf(d) : 0.f;
    }
}

// ---------------- build A_t fp16 (vectorized 8/thread): A2[t][m][n] ----------
__global__ __launch_bounds__(256) void build_A2(
    const float* __restrict__ dtw, const float* __restrict__ adj,
    const float* __restrict__ spec, const float* __restrict__ td,
    const float* __restrict__ dsA, const float* __restrict__ dsS,
    const int* __restrict__ sr_ptr, _Float16* __restrict__ A2) {
    int idx = blockIdx.x * blockDim.x + threadIdx.x;   // NN*NN/8 threads
    int m = idx >> 7;
    int n0 = (idx & 127) << 3;
    size_t base = (size_t)m * NN + n0;
    float sr = (float)sr_ptr[0];
    float dsSm = dsS[m], dsAm = dsA[m];
    float dv[8], av[8], sv[8], tv[8], sn[8];
    *(float4*)&dv[0] = *(const float4*)(dtw + base);
    *(float4*)&dv[4] = *(const float4*)(dtw + base + 4);
    *(float4*)&av[0] = *(const float4*)(adj + base);
    *(float4*)&av[4] = *(const float4*)(adj + base + 4);
    *(float4*)&sv[0] = *(const float4*)(spec + base);
    *(float4*)&sv[4] = *(const float4*)(spec + base + 4);
    *(float4*)&tv[0] = *(const float4*)(td + base);
    *(float4*)&tv[4] = *(const float4*)(td + base + 4);
    *(float4*)&sn[0] = *(const float4*)(dsS + n0);
    *(float4*)&sn[4] = *(const float4*)(dsS + n0 + 4);
    float base2[8], base3[8], tind[8];
    bool nz[8];
#pragma unroll
    for (int q = 0; q < 8; ++q) {
        int n = n0 + q;
        float I = (m == n) ? 1.f : 0.f;
        float Lspec = I - dsSm * sv[q] * sn[q];
        float Ladj  = I - dsAm * av[q] * dsA[n0 + q];
        tind[q] = (float)TT - ceilf(fabsf(tv[q]) / sr);
        base2[q] = 0.5f * (Lspec + I);
        base3[q] = (Lspec + Ladj + I) * (1.f / 3.f);
        nz[q] = (dv[q] != 0.f);
    }
#pragma unroll
    for (int t = 0; t < TT; ++t) {
        __attribute__((aligned(16))) _Float16 o[8];
#pragma unroll
        for (int q = 0; q < 8; ++q) {
            bool act = nz[q] && ((float)(t + 1) > tind[q]);
            float a = (t == TT - 1) ? base3[q] + (act ? dv[q] * (1.f / 3.f) : 0.f)
                                    : base2[q] + (act ? dv[q] * 0.5f : 0.f);
            o[q] = (_Float16)a;
        }
        *(uint4*)(A2 + ((size_t)t * NN + m) * KX + n0) = *(uint4*)&o[0];
    }
}

// ---------------- build cat (transposed, fp16): cat[z][col][node], col=b*72+k1 ----
__global__ __launch_bounds__(256) void build_cat(
    const float* __restrict__ inputs, const float* __restrict__ states,
    const _Float16* __restrict__ rall, _Float16* __restrict__ cat,
    int tbase, int pass2) {
    __shared__ float hs[64][68];
    __shared__ float rs[64][68];
    const int z = blockIdx.z, t = tbase + z;
    const int b = blockIdx.y, nb = blockIdx.x;
    const int tid = threadIdx.x;
    const float* sb = states + ((size_t)t * BB + b) * NH + (size_t)nb * 4096;
    const float4* src = (const float4*)sb;
#pragma unroll
    for (int q = 0; q < 4; ++q) {
        float4 v = src[tid * 4 + q];
        int fi = tid * 16 + q * 4;
        *(float4*)&hs[fi >> 6][fi & 63] = v;
    }
    if (pass2) {
        const _Float16* rb = rall + ((size_t)t * BB + b) * NH + (size_t)nb * 4096;
#pragma unroll
        for (int i = 0; i < 16; ++i) {
            int fi = tid * 16 + i;
            rs[fi >> 6][fi & 63] = (float)rb[fi];
        }
    }
    __syncthreads();
    _Float16* catz = cat + (size_t)z * NC2 * KX;
    int jp = tid >> 2, ni = (tid & 3) << 4;
    int col = b * BPAD + 1 + jp;   // feature k1 = 1 + jp
    __attribute__((aligned(16))) _Float16 hib[16];
#pragma unroll
    for (int i = 0; i < 16; ++i) {
        float v = hs[ni + i][jp];
        if (pass2) v *= rs[ni + i][jp];
        hib[i] = (_Float16)v;
    }
    size_t dst = (size_t)col * KX + nb * 64 + ni;
    *(uint4*)(catz + dst)     = *(uint4*)&hib[0];
    *(uint4*)(catz + dst + 8) = *(uint4*)&hib[8];
    if (tid < 64) {
        float v = inputs[((size_t)b * TT + t) * NN + nb * 64 + tid];
        catz[(size_t)(b * BPAD) * KX + nb * 64 + tid] = (_Float16)v;   // k1 = 0 (x)
    }
}

// ---------------- pass-2 cat update in place (C=12 path): cat *= r ----------
__global__ __launch_bounds__(256) void scale_cat(
    const _Float16* __restrict__ rall, _Float16* __restrict__ cat, int tbase) {
    __shared__ float rs[64][68];    // rs[node][hh]
    const int z = blockIdx.z, t = tbase + z;
    const int b = blockIdx.y, nb = blockIdx.x;
    const int tid = threadIdx.x;
    const _Float16* rb = rall + ((size_t)t * BB + b) * NH + (size_t)nb * 4096;
    {
        h8 r0 = *(const h8*)(rb + tid * 16);
        h8 r1 = *(const h8*)(rb + tid * 16 + 8);
        int node = tid >> 2, c0 = (tid & 3) << 4;
#pragma unroll
        for (int i = 0; i < 8; ++i) {
            rs[node][c0 + i]     = (float)r0[i];
            rs[node][c0 + 8 + i] = (float)r1[i];
        }
    }
    __syncthreads();
    _Float16* catz = cat + (size_t)z * NC2 * KX;
    const int jp = tid >> 2, ni = (tid & 3) << 4;
    const int col = b * BPAD + 1 + jp;
    size_t dst = (size_t)col * KX + nb * 64 + ni;
    h8 v0 = *(const h8*)(catz + dst);
    h8 v1 = *(const h8*)(catz + dst + 8);
    h8 o0, o1;
#pragma unroll
    for (int i = 0; i < 8; ++i) {
        o0[i] = (_Float16)((float)v0[i] * rs[ni + i][jp]);
        o1[i] = (_Float16)((float)v1[i] * rs[ni + 8 + i][jp]);
    }
    *(h8*)(catz + dst)     = o0;
    *(h8*)(catz + dst + 8) = o1;
}

// ---- MFMA GEMM (fp16, K=1024): 128x256 block, 128x64/wave, 2-buf (48KB LDS,
// ---- 3 blocks/CU), 32x32x16 MFMA — pinned config (r15/r17, 123 us) ----
__global__ __launch_bounds__(256, 3) void gemm_f16(
    const _Float16* __restrict__ A2, const _Float16* __restrict__ cat,
    _Float16* __restrict__ P, int tbase) {
    __shared__ __align__(16) _Float16 smem[NBUF * (BM + BN) * BKK];   // 48 KB
    _Float16* Asb = smem;                       // [NBUF][BM*BKK]
    _Float16* Xsb = smem + NBUF * BM * BKK;     // [NBUF][BN*BKK]
    const int tid = threadIdx.x;
    const int lane = tid & 63;
    const int wid = tid >> 6;
    int bid = blockIdx.x;
    int l = (bid & 7) * ((int)gridDim.x >> 3) + (bid >> 3);
    int z = l / 72; int r = l - z * 72;
    int g  = r / 12, w = r - g * 12;
    int gy = g & 1, gx = g >> 1;          // gx in [0,3)
    int by = (gy << 2) + (w & 3);         // 0..7
    int bx = gx * 3 + (w >> 2);           // 0..8
    const int m0 = by * BM;
    const int n0 = bx * BN;
    const _Float16* Ab = A2 + (size_t)(tbase + z) * NN * KX + (size_t)m0 * KX;
    const _Float16* Xb = cat + (size_t)z * NC2 * KX + (size_t)n0 * KX;

    f32x16 acc[4][2];
#pragma unroll
    for (int i = 0; i < 4; ++i)
#pragma unroll
        for (int j = 0; j < 2; ++j)
#pragma unroll
            for (int q = 0; q < 16; ++q) acc[i][j][q] = 0.f;

    const int wn = wid << 6;       // wave's 64-col slice
    const int rl = lane & 31;      // row/col within 32-tile
    const int ko = lane >> 5;      // k-octet selector (0/1)

    auto stage = [&](int buf, int k0) {
#pragma unroll
        for (int c = 0; c < 2; ++c) {
            int p = c * 256 + tid;          // 0..511
            int row = p & 127;
            int kg  = p >> 7;               // 0..3
            gload16(Ab + (size_t)row * KX + k0 + kg * 8, &Asb[(size_t)(buf * BM * BKK + p * 8)]);
        }
#pragma unroll
        for (int c = 0; c < 4; ++c) {
            int p = c * 256 + tid;          // 0..1023
            int row = p & 255;
            int kg  = p >> 8;               // 0..3
            gload16(Xb + (size_t)row * KX + k0 + kg * 8, &Xsb[(size_t)(buf * BN * BKK + p * 8)]);
        }
    };
    auto compute = [&](int buf) {
#pragma unroll
        for (int ks = 0; ks < 2; ++ks) {           // k-halves of the 32-k slab
            const int oct = (ks << 1) + ko;        // octet 0..3 within slab
            h8 a[4], x[2];
#pragma unroll
            for (int i = 0; i < 4; ++i)
                a[i] = *(const h8*)&Asb[(size_t)(buf * BM * BKK + ((oct << 7) + (i << 5) + rl) * 8)];
#pragma unroll
            for (int j = 0; j < 2; ++j)
                x[j] = *(const h8*)&Xsb[(size_t)(buf * BN * BKK + ((oct << 8) + wn + (j << 5) + rl) * 8)];
#pragma unroll
            for (int i = 0; i < 4; ++i)
#pragma unroll
                for (int j = 0; j < 2; ++j)
                    acc[i][j] = __builtin_amdgcn_mfma_f32_32x32x16_f16(a[i], x[j], acc[i][j], 0, 0, 0);
        }
    };

    stage(0, 0);
    stage(1, BKK);
    const int nk = KX / BKK;   // 32
    for (int it = 0; it < nk; ++it) {
        if (it + 1 < nk) {
            asm volatile("s_waitcnt vmcnt(6)" ::: "memory");
        } else {
            asm volatile("s_waitcnt vmcnt(0)" ::: "memory");
        }
        __builtin_amdgcn_s_barrier();      // cur fully written (all waves)
        compute(it & 1);
        __builtin_amdgcn_s_barrier();      // all waves done reading cur before re-stage
        if (it + 2 < nk) stage(it & 1, (it + 2) * BKK);
    }

    // ---- epilogue: two 64-row passes through LDS (fits 48KB), uint4 stores ----
    _Float16* Pt = smem;                   // 64 x PTS fp16 = 33 KB per pass
    _Float16* Pz = P + (size_t)z * NN * NC2;
#pragma unroll
    for (int h = 0; h < 2; ++h) {
        if (h) __syncthreads();            // pass-0 reads done before overwrite
#pragma unroll
        for (int i2 = 0; i2 < 2; ++i2) {   // acc row-tiles 2h, 2h+1
            const int i = (h << 1) + i2;
#pragma unroll
            for (int j = 0; j < 2; ++j)
#pragma unroll
                for (int q = 0; q < 16; ++q) {
                    int row = (i2 << 5) + (q & 3) + ((q >> 2) << 3) + (ko << 2);
                    Pt[row * PTS + wn + (j << 5) + rl] = (_Float16)acc[i][j][q];
                }
        }
        __syncthreads();
#pragma unroll
        for (int c = 0; c < 8; ++c) {
            int u = c * 256 + tid;          // 0..2047
            int rr = u >> 5;                // 0..63
            int cc = u & 31;                // 0..31
            uint4 v = *(const uint4*)&Pt[rr * PTS + cc * 8];
            *(uint4*)(Pz + (size_t)(m0 + (h << 6) + rr) * NC2 + n0 + cc * 8) = v;
        }
    }
}

// ---------------- fused pass-1 stage2 (MFMA): prefix over zc t's in AGPRs ----
// rall writes staged through LDS (coalesced uint4).
__global__ __launch_bounds__(256) void stage2m(const _Float16* __restrict__ P,
                                               const float* __restrict__ W,
                                               const float* __restrict__ bias,
                                               float* __restrict__ cum,
                                               _Float16* __restrict__ rall,
                                               int tbase, int zc) {
    __shared__ __align__(16) _Float16 Pl[TT * NC2];   // 55.3 KB
    __shared__ _Float16 Wl[K1 * 128];                 // 16.6 KB
    __shared__ __align__(16) _Float16 Rl[BB * 128];   // 8 KB r staging
    const int m = blockIdx.x;
    const int tid = threadIdx.x;
    const int lane = tid & 63, wid = tid >> 6;
    const int fl = lane & 15, fh = lane >> 4;
    for (int i = tid; i < K1 * 128; i += 256) Wl[i] = (_Float16)W[i];
    const int chunks = zc * (NC2 / 8);
    for (int idx = tid; idx < chunks; idx += 256) {
        int z = idx / (NC2 / 8), off = idx - z * (NC2 / 8);
        gload16(P + ((size_t)z * NN + m) * NC2 + off * 8, (char*)Pl + (size_t)idx * 16);
    }
    __syncthreads();
    const int nt0 = wid * 2;
    h8 wf[2][2];
    float w64[2], bvv[2];
#pragma unroll
    for (int n2 = 0; n2 < 2; ++n2) {
        int k2 = (nt0 + n2) * 16 + fl;
        w64[n2] = (float)Wl[64 * 128 + k2];
        bvv[n2] = bias[k2];
#pragma unroll
        for (int ks = 0; ks < 2; ++ks) {
            h8 tmp;
#pragma unroll
            for (int j = 0; j < 8; ++j)
                tmp[j] = Wl[(ks * 32 + fh * 8 + j) * 128 + k2];
            wf[n2][ks] = tmp;
        }
    }
    f32x4 g[2][2];
    if (tbase > 0) {
#pragma unroll
        for (int mt = 0; mt < 2; ++mt)
#pragma unroll
            for (int n2 = 0; n2 < 2; ++n2)
#pragma unroll
                for (int r4 = 0; r4 < 4; ++r4) {
                    int b = mt * 16 + fh * 4 + r4;
                    int k2 = (nt0 + n2) * 16 + fl;
                    g[mt][n2][r4] = cum[(size_t)b * (2 * NH) + (size_t)m * 128 + k2];
                }
    } else {
#pragma unroll
        for (int mt = 0; mt < 2; ++mt)
#pragma unroll
            for (int n2 = 0; n2 < 2; ++n2)
                g[mt][n2] = {0.f, 0.f, 0.f, 0.f};
    }
#pragma unroll 1
    for (int z = 0; z < zc; ++z) {
        const _Float16* Pz = &Pl[z * NC2];
        h8 af[2][2];
#pragma unroll
        for (int mt = 0; mt < 2; ++mt)
#pragma unroll
            for (int ks = 0; ks < 2; ++ks)
                af[mt][ks] = *(const h8*)&Pz[(mt * 16 + fl) * BPAD + ks * 32 + fh * 8];
#pragma unroll
        for (int mt = 0; mt < 2; ++mt)
#pragma unroll
            for (int n2 = 0; n2 < 2; ++n2)
#pragma unroll
                for (int ks = 0; ks < 2; ++ks)
                    g[mt][n2] = __builtin_amdgcn_mfma_f32_16x16x32_f16(
                        af[mt][ks], wf[n2][ks], g[mt][n2], 0, 0, 0);
        float p64[2][4];
#pragma unroll
        for (int mt = 0; mt < 2; ++mt)
#pragma unroll
            for (int r4 = 0; r4 < 4; ++r4)
                p64[mt][r4] = (float)Pz[(mt * 16 + fh * 4 + r4) * BPAD + 64];
#pragma unroll
        for (int mt = 0; mt < 2; ++mt)
#pragma unroll
            for (int n2 = 0; n2 < 2; ++n2)
#pragma unroll
                for (int r4 = 0; r4 < 4; ++r4)
                    g[mt][n2][r4] += p64[mt][r4] * w64[n2] + bvv[n2];
        if (m < 512) {   // r-half: f = m*128 + k2 < NH
            const int t = tbase + z;
#pragma unroll
            for (int mt = 0; mt < 2; ++mt)
#pragma unroll
                for (int n2 = 0; n2 < 2; ++n2)
#pragma unroll
                    for (int r4 = 0; r4 < 4; ++r4) {
                        int b = mt * 16 + fh * 4 + r4;
                        int k2 = (nt0 + n2) * 16 + fl;
                        Rl[b * 128 + k2] = (_Float16)(1.f / (1.f + expf(-g[mt][n2][r4])));
                    }
            __syncthreads();
#pragma unroll
            for (int c = 0; c < 2; ++c) {
                int u = c * 256 + tid;      // 0..511
                int b = u >> 4;             // 0..31
                int k2q = (u & 15) << 3;    // 0..120 step 8
                uint4 v = *(const uint4*)&Rl[b * 128 + k2q];
                *(uint4*)(rall + ((size_t)t * BB + b) * NH + (size_t)m * 128 + k2q) = v;
            }
            __syncthreads();   // Rl reuse safe for next z
        }
    }
    if (m >= 512 || tbase + zc < TT) {
#pragma unroll
        for (int mt = 0; mt < 2; ++mt)
#pragma unroll
            for (int n2 = 0; n2 < 2; ++n2)
#pragma unroll
                for (int r4 = 0; r4 < 4; ++r4) {
                    int b = mt * 16 + fh * 4 + r4;
                    int k2 = (nt0 + n2) * 16 + fl;
                    cum[(size_t)b * (2 * NH) + (size_t)m * 128 + k2] = g[mt][n2][r4];
                }
    }
}

// ------- pass-2 stage2 fused w/ finalize (C=12): gcn2 = sumP@W2 + 12*b2 -> out -------
__global__ __launch_bounds__(128) void stage2p2f(const _Float16* __restrict__ P,
                                                 const float* __restrict__ W,
                                                 const float* __restrict__ bias,
                                                 const float* __restrict__ cum1,
                                                 const float* __restrict__ states,
                                                 float* __restrict__ out, int zc) {
    __shared__ float Pl[K1][37];
    __shared__ float Wl[K1 * 64];
    const int m = blockIdx.x;
    for (int i = threadIdx.x; i < K1 * 64; i += 128) Wl[i] = W[i];
    float s[3][8];
#pragma unroll
    for (int c = 0; c < 3; ++c)
#pragma unroll
        for (int q = 0; q < 8; ++q) s[c][q] = 0.f;
    for (int z = 0; z < zc; ++z) {
        const _Float16* Pz = P + ((size_t)z * NN + m) * NC2;
#pragma unroll
        for (int c = 0; c < 3; ++c) {
            int ch = c * 128 + threadIdx.x;
            if (ch < NC2 / 8) {
                h8 v = *(const h8*)(Pz + ch * 8);
#pragma unroll
                for (int q = 0; q < 8; ++q) s[c][q] += (float)v[q];
            }
        }
    }
#pragma unroll
    for (int c = 0; c < 3; ++c) {
        int ch = c * 128 + threadIdx.x;
        if (ch < NC2 / 8) {
#pragma unroll
            for (int q = 0; q < 8; ++q) {
                int col = ch * 8 + q;
                int b = col / BPAD, k = col - b * BPAD;
                if (k < K1) Pl[k][b] = s[c][q];
            }
        }
    }
    __syncthreads();
    const int k2q = (threadIdx.x & 15) << 2;   // 0..60
    const int bq4 = (threadIdx.x >> 4) << 2;   // 0,4,..,28
    const float4 bv = *(const float4*)(bias + k2q);

    for (int bi = 0; bi < 4; ++bi) {
        const int b = bq4 + bi;
        float a0 = 0.f, a1 = 0.f, a2 = 0.f, a3 = 0.f;
#pragma unroll 4
        for (int k = 0; k < K1; ++k) {
            float p = Pl[k][b];
            float4 w4 = *(const float4*)&Wl[k * 64 + k2q];
            a0 += p * w4.x; a1 += p * w4.y; a2 += p * w4.z; a3 += p * w4.w;
        }
        const int f = m * HH + k2q;
        float g0 = a0 + zc * bv.x, g1 = a1 + zc * bv.y;
        float g2 = a2 + zc * bv.z, g3 = a3 + zc * bv.w;
        const float4 ul = *(const float4*)(cum1 + (size_t)b * 2 * NH + NH + f);
        const float4 hv = *(const float4*)(states + ((size_t)(TT - 1) * BB + b) * NH + f);
        float4 ov;
        { float u = 1.f / (1.f + expf(-ul.x)); ov.x = u * hv.x + (1.f - u) * tanhf(g0); }
        { float u = 1.f / (1.f + expf(-ul.y)); ov.y = u * hv.y + (1.f - u) * tanhf(g1); }
        { float u = 1.f / (1.f + expf(-ul.z)); ov.z = u * hv.z + (1.f - u) * tanhf(g2); }
        { float u = 1.f / (1.f + expf(-ul.w)); ov.w = u * hv.w + (1.f - u) * tanhf(g3); }
        *(float4*)(out + (size_t)b * NH + f) = ov;
        *(float4*)(out + (size_t)BB * NH + (size_t)b * NH + f) = ov;
    }
}

// ---------------- fallback pass-2 stage2 (+ separate finalize) ------
__global__ __launch_bounds__(128) void stage2p2(const _Float16* __restrict__ P,
                                                const float* __restrict__ W,
                                                const float* __restrict__ bias,
                                                float* __restrict__ cum, int zc) {
    __shared__ float Pl[K1][37];
    __shared__ float Wl[K1 * 64];
    const int m = blockIdx.x;
    for (int i = threadIdx.x; i < K1 * 64; i += 128) Wl[i] = W[i];
    for (int i = threadIdx.x; i < NCOLS; i += 128) {
        int b = i / K1, k = i - b * K1;
        float s = 0.f;
        for (int z = 0; z < zc; ++z)
            s += (float)P[((size_t)z * NN + m) * NC2 + b * BPAD + k];
        Pl[k][b] = s;
    }
    __syncthreads();
    const int k2q = (threadIdx.x & 15) << 2;
    const int bq4 = (threadIdx.x >> 4) << 2;
    const float4 bv = *(const float4*)(bias + k2q);

    for (int bi = 0; bi < 4; ++bi) {
        const int b = bq4 + bi;
        float a0 = 0.f, a1 = 0.f, a2 = 0.f, a3 = 0.f;
#pragma unroll 4
        for (int k = 0; k < K1; ++k) {
            float p = Pl[k][b];
            float4 w4 = *(const float4*)&Wl[k * 64 + k2q];
            a0 += p * w4.x; a1 += p * w4.y; a2 += p * w4.z; a3 += p * w4.w;
        }
        float* cp = cum + (size_t)b * NN * 64 + (size_t)m * 64 + k2q;
        float4 c4 = *(float4*)cp;
        c4.x += a0 + zc * bv.x; c4.y += a1 + zc * bv.y;
        c4.z += a2 + zc * bv.z; c4.w += a3 + zc * bv.w;
        *(float4*)cp = c4;
    }
}

__global__ void finalize(const float* __restrict__ cum1, const float* __restrict__ cum2,
                         const float* __restrict__ states, float* __restrict__ out) {
    int idx = blockIdx.x * blockDim.x + threadIdx.x;
    if (idx >= BB * NH) return;
    int b = idx >> 16;
    int f = idx & (NH - 1);
    float u = 1.f / (1.f + expf(-cum1[(size_t)b * 2 * NH + NH + f]));
    float h = states[((size_t)(TT - 1) * BB + b) * NH + f];
    float c = tanhf(cum2[idx]);
    float o = u * h + (1.f - u) * c;
    out[idx] = o;
    out[(size_t)BB * NH + idx] = o;
}

extern "C" void kernel_launch(void* const* d_in, const int* in_sizes, int n_in,
                              void* d_out, int out_size, void* d_ws, size_t ws_size,
                              hipStream_t stream) {
    const float* inputs = (const float*)d_in[0];
    const float* states = (const float*)d_in[1];
    const float* dtw    = (const float*)d_in[2];
    const float* adj    = (const float*)d_in[3];
    const float* spec   = (const float*)d_in[4];
    const float* td     = (const float*)d_in[5];
    const float* W1     = (const float*)d_in[6];
    const float* b1     = (const float*)d_in[7];
    const float* W2     = (const float*)d_in[8];
    const float* b2     = (const float*)d_in[9];
    const int*   sr     = (const int*)d_in[10];
    float* out = (float*)d_out;

    char* ws = (char*)d_ws;
    const size_t szA2   = (size_t)TT * NN * KX * 2;     // 25.2 MB
    const size_t szCum1 = (size_t)BB * 2 * NH * 4;      // 16.8 MB
    const size_t szCum2 = (size_t)BB * NH * 4;          // 8.4 MB
    const size_t szRall = (size_t)TT * BB * NH * 2;     // 50.3 MB

    _Float16* A2  = (_Float16*)ws;
    float* cum1 = (float*)(ws + szA2);
    float* cum2 = (float*)(ws + szA2 + szCum1);
    float* dsA  = (float*)(ws + szA2 + szCum1 + szCum2);
    float* dsS  = (float*)(ws + szA2 + szCum1 + szCum2 + 4096);
    _Float16* rall = (_Float16*)(ws + szA2 + szCum1 + szCum2 + 8192);
    size_t offRest = szA2 + szCum1 + szCum2 + 8192 + szRall;

    rowsum_rsqrt2<<<2 * NN, 256, 0, stream>>>(adj, spec, dsA, dsS);
    build_A2<<<(NN * NN / 8) / 256, 256, 0, stream>>>(dtw, adj, spec, td, dsA, dsS, sr, A2);

    const size_t szCatZ = (size_t)NC2 * KX * 2;         // 4.72 MB per t
    const size_t szPZ   = (size_t)NN * NC2 * 2;         // 4.72 MB per t
    int C;
    if      (ws_size >= offRest + 12 * (szCatZ + szPZ)) C = 12;
    else if (ws_size >= offRest + 4 * (szCatZ + szPZ))  C = 4;
    else                                                C = 1;
    _Float16* cat = (_Float16*)(ws + offRest);
    _Float16* P16 = (_Float16*)(ws + offRest + (size_t)C * szCatZ);

    if (C == 12) {
        // pass 1
        build_cat<<<dim3(16, 32, 12), 256, 0, stream>>>(inputs, states, nullptr, cat, 0, 0);
        gemm_f16<<<dim3(72 * 12), 256, 0, stream>>>(A2, cat, P16, 0);
        stage2m<<<NN, 256, 0, stream>>>(P16, W1, b1, cum1, rall, 0, 12);
        // pass 2: scale cat in place, gemm, fused stage2+finalize
        scale_cat<<<dim3(16, 32, 12), 256, 0, stream>>>(rall, cat, 0);
        gemm_f16<<<dim3(72 * 12), 256, 0, stream>>>(A2, cat, P16, 0);
        stage2p2f<<<NN, 128, 0, stream>>>(P16, W2, b2, cum1, states, out, 12);
    } else {
        hipMemsetAsync(cum2, 0, szCum2, stream);
        for (int tb = 0; tb < TT; tb += C) {
            build_cat<<<dim3(16, 32, C), 256, 0, stream>>>(inputs, states, nullptr, cat, tb, 0);
            gemm_f16<<<dim3(72 * C), 256, 0, stream>>>(A2, cat, P16, tb);
            stage2m<<<NN, 256, 0, stream>>>(P16, W1, b1, cum1, rall, tb, C);
        }
        for (int tb = 0; tb < TT; tb += C) {
            build_cat<<<dim3(16, 32, C), 256, 0, stream>>>(inputs, states, rall, cat, tb, 1);
            gemm_f16<<<dim3(72 * C), 256, 0, stream>>>(A2, cat, P16, tb);
            stage2p2<<<NN, 128, 0, stream>>>(P16, W2, b2, cum2, C);
        }
        finalize<<<(BB * NH + 255) / 256, 256, 0, stream>>>(cum1, cum2, states, out);
    }
}